// Round 1
// baseline (5942.622 us; speedup 1.0000x reference)
//
#include <hip/hip_runtime.h>
#include <cstddef>

#define N_NODES 100000
#define N_EDGES 1600000
#define D 256

// ---------------------------------------------------------------------------
// Kernel 1: edge scatter. One wave (64 lanes) per edge: lanes read the 256-f
// source row as float4 (1KB coalesced) and atomically accumulate into the
// destination row living in d_out. Lane 0 also bumps deg[dst].
// ---------------------------------------------------------------------------
__global__ __launch_bounds__(256) void scatter_kernel(
    const float* __restrict__ feat,
    const int* __restrict__ src,
    const int* __restrict__ dst,
    float* __restrict__ S,      // d_out used as the summed-accumulator
    float* __restrict__ deg)
{
    const int gtid   = blockIdx.x * blockDim.x + threadIdx.x;
    const int wave   = gtid >> 6;
    const int lane   = gtid & 63;
    const int nwaves = (gridDim.x * blockDim.x) >> 6;

    for (int e = wave; e < N_EDGES; e += nwaves) {
        const int s = src[e];
        const int d = dst[e];
        if (lane == 0) unsafeAtomicAdd(&deg[d], 1.0f);
        const float4 v = ((const float4*)(feat + (size_t)s * D))[lane];
        float* o = S + (size_t)d * D + lane * 4;
        unsafeAtomicAdd(o + 0, v.x);
        unsafeAtomicAdd(o + 1, v.y);
        unsafeAtomicAdd(o + 2, v.z);
        unsafeAtomicAdd(o + 3, v.w);
    }
}

// ---------------------------------------------------------------------------
// Kernel 2: fused in-place GEMM.
//   out[i][j] = sum_k feat[i][k]*Ws[j][k] + invd[i]*sum_k S[i][k]*Wn[j][k] + b[j]
// Treated as one K=512 GEMM: A' = [feat | S*invd], B' = [Ws ; Wn].
// Block = 256 threads, BM=64 rows x BN=256 (ALL cols) -> each block owns its
// rows exclusively, reads S rows fully during the K-loop, writes them only in
// the epilogue => in-place is race-free.
// ---------------------------------------------------------------------------
#define BM 64
#define BK 16

__global__ __launch_bounds__(256) void fused_gemm_kernel(
    const float* __restrict__ feat,
    const float* __restrict__ w_neigh,
    const float* __restrict__ w_self,
    const float* __restrict__ b_self,
    const float* __restrict__ deg,
    float* __restrict__ out)    // in: summed S, out: rst (in-place per row-block)
{
    __shared__ float At[BK][BM + 4];   // +4 pad keeps 16B align, kills conflicts
    __shared__ float Bt[BK][256];

    const int tid  = threadIdx.x;
    const int i0   = blockIdx.x * BM;
    const int trow = tid >> 4;    // 0..15 -> 4 rows each
    const int tcol = tid & 15;    // 0..15 -> 16 cols each
    const int m_load = tid >> 2;  // 0..63 (A staging row)
    const int kq     = tid & 3;   // 0..3  (A staging k-quad)

    const int  arow    = i0 + m_load;
    const bool arow_ok = arow < N_NODES;
    float invd = 1.0f;
    if (arow_ok) invd = 1.0f / fmaxf(deg[arow], 1.0f);

    float acc[4][16];
#pragma unroll
    for (int r = 0; r < 4; ++r)
#pragma unroll
        for (int c = 0; c < 16; ++c) acc[r][c] = 0.0f;

    for (int kc = 0; kc < (2 * D) / BK; ++kc) {
        const int  kb        = kc * BK;
        const bool self_part = (kb < D);
        const int  kbase     = self_part ? kb : (kb - D);

        // ---- fetch A fragment (global) ----
        float4 va = make_float4(0.f, 0.f, 0.f, 0.f);
        if (arow_ok) {
            const float* ap = self_part ? feat : out;   // out holds S
            va = *(const float4*)(ap + (size_t)arow * D + kbase + kq * 4);
            if (!self_part) { va.x *= invd; va.y *= invd; va.z *= invd; va.w *= invd; }
        }
        // ---- fetch B fragment: row j = tid of Ws or Wn, 16 floats ----
        const float* W = self_part ? w_self : w_neigh;
        const float4* wp = (const float4*)(W + (size_t)tid * D + kbase);
        const float4 w0 = wp[0], w1 = wp[1], w2 = wp[2], w3 = wp[3];

        __syncthreads();   // previous iteration's LDS reads done
        At[kq * 4 + 0][m_load] = va.x;
        At[kq * 4 + 1][m_load] = va.y;
        At[kq * 4 + 2][m_load] = va.z;
        At[kq * 4 + 3][m_load] = va.w;
        Bt[ 0][tid] = w0.x; Bt[ 1][tid] = w0.y; Bt[ 2][tid] = w0.z; Bt[ 3][tid] = w0.w;
        Bt[ 4][tid] = w1.x; Bt[ 5][tid] = w1.y; Bt[ 6][tid] = w1.z; Bt[ 7][tid] = w1.w;
        Bt[ 8][tid] = w2.x; Bt[ 9][tid] = w2.y; Bt[10][tid] = w2.z; Bt[11][tid] = w2.w;
        Bt[12][tid] = w3.x; Bt[13][tid] = w3.y; Bt[14][tid] = w3.z; Bt[15][tid] = w3.w;
        __syncthreads();

#pragma unroll
        for (int k = 0; k < BK; ++k) {
            const float4 a  = *(const float4*)&At[k][trow * 4];
            const float4 b0 = *(const float4*)&Bt[k][tcol * 16 + 0];
            const float4 b1 = *(const float4*)&Bt[k][tcol * 16 + 4];
            const float4 b2 = *(const float4*)&Bt[k][tcol * 16 + 8];
            const float4 b3 = *(const float4*)&Bt[k][tcol * 16 + 12];
            const float av[4] = {a.x, a.y, a.z, a.w};
            const float bv[16] = {b0.x, b0.y, b0.z, b0.w, b1.x, b1.y, b1.z, b1.w,
                                  b2.x, b2.y, b2.z, b2.w, b3.x, b3.y, b3.z, b3.w};
#pragma unroll
            for (int r = 0; r < 4; ++r)
#pragma unroll
                for (int c = 0; c < 16; ++c)
                    acc[r][c] = fmaf(av[r], bv[c], acc[r][c]);
        }
    }

    // ---- epilogue: add bias, write rows (each row owned by this block only)
    float4 bias[4];
#pragma unroll
    for (int c4 = 0; c4 < 4; ++c4)
        bias[c4] = *(const float4*)&b_self[tcol * 16 + c4 * 4];

#pragma unroll
    for (int r = 0; r < 4; ++r) {
        const int row = i0 + trow * 4 + r;
        if (row < N_NODES) {
            float* op = out + (size_t)row * D + tcol * 16;
#pragma unroll
            for (int c4 = 0; c4 < 4; ++c4) {
                float4 v;
                v.x = acc[r][c4 * 4 + 0] + bias[c4].x;
                v.y = acc[r][c4 * 4 + 1] + bias[c4].y;
                v.z = acc[r][c4 * 4 + 2] + bias[c4].z;
                v.w = acc[r][c4 * 4 + 3] + bias[c4].w;
                *(float4*)(op + c4 * 4) = v;
            }
        }
    }
}

// ---------------------------------------------------------------------------
extern "C" void kernel_launch(void* const* d_in, const int* in_sizes, int n_in,
                              void* d_out, int out_size, void* d_ws, size_t ws_size,
                              hipStream_t stream) {
    const float* feat    = (const float*)d_in[0];
    const int*   src     = (const int*)d_in[1];
    const int*   dst     = (const int*)d_in[2];
    const float* w_neigh = (const float*)d_in[3];
    const float* w_self  = (const float*)d_in[4];
    const float* b_self  = (const float*)d_in[5];
    float* out = (float*)d_out;
    float* deg = (float*)d_ws;            // N_NODES floats

    // zero the accumulators (harness poisons d_out/d_ws; replays leave state)
    hipMemsetAsync(out, 0, (size_t)N_NODES * D * sizeof(float), stream);
    hipMemsetAsync(deg, 0, (size_t)N_NODES * sizeof(float), stream);

    scatter_kernel<<<4096, 256, 0, stream>>>(feat, src, dst, out, deg);

    const int nblocks = (N_NODES + BM - 1) / BM;   // 1563
    fused_gemm_kernel<<<nblocks, 256, 0, stream>>>(feat, w_neigh, w_self, b_self,
                                                   deg, out);
}

// Round 2
// 1046.422 us; speedup vs baseline: 5.6790x; 5.6790x over previous
//
#include <hip/hip_runtime.h>
#include <cstddef>

#define N_NODES 100000
#define N_EDGES 1600000
#define D 256

// ---------------------------------------------------------------------------
// CSR path workspace layout (ints):
//   [0, N)            counts / cursor (reused)
//   [N, 2N+1)         row_ptr
//   [2N+16, ...)      col (N_EDGES)
// ---------------------------------------------------------------------------
#define WS_COUNTS 0
#define WS_ROWPTR (N_NODES)
#define WS_COL    (2 * N_NODES + 16)

__global__ __launch_bounds__(256) void hist_kernel(
    const int* __restrict__ dst, int* __restrict__ counts)
{
    const int i = blockIdx.x * 256 + threadIdx.x;
    if (i < N_EDGES) atomicAdd(&counts[dst[i]], 1);
}

// Single-workgroup chunked exclusive scan: row_ptr[0]=0, row_ptr[i+1]=incl sum
__global__ __launch_bounds__(1024) void scan_kernel(
    const int* __restrict__ counts, int* __restrict__ row_ptr)
{
    __shared__ int sdata[1024];
    __shared__ int s_carry;
    const int tid = threadIdx.x;
    if (tid == 0) { s_carry = 0; row_ptr[0] = 0; }
    __syncthreads();
    for (int base = 0; base < N_NODES; base += 1024) {
        const int i = base + tid;
        int v = (i < N_NODES) ? counts[i] : 0;
        sdata[tid] = v;
        __syncthreads();
        for (int off = 1; off < 1024; off <<= 1) {
            int t = (tid >= off) ? sdata[tid - off] : 0;
            __syncthreads();
            sdata[tid] += t;
            __syncthreads();
        }
        const int carry = s_carry;
        if (i < N_NODES) row_ptr[i + 1] = carry + sdata[tid];
        __syncthreads();
        if (tid == 1023) s_carry = carry + sdata[1023];
        __syncthreads();
    }
}

__global__ __launch_bounds__(256) void fill_kernel(
    const int* __restrict__ src, const int* __restrict__ dst,
    const int* __restrict__ row_ptr, int* __restrict__ cursor,
    int* __restrict__ col)
{
    const int i = blockIdx.x * 256 + threadIdx.x;
    if (i < N_EDGES) {
        const int d = dst[i];
        const int pos = atomicAdd(&cursor[d], 1);
        col[row_ptr[d] + pos] = src[i];
    }
}

// One wave per node: gather-sum neighbor rows (float4/lane = full 256-f row),
// scale by 1/max(deg,1), write the mean row once. No atomics.
__global__ __launch_bounds__(256) void aggregate_kernel(
    const float* __restrict__ feat, const int* __restrict__ row_ptr,
    const int* __restrict__ col, float* __restrict__ out)
{
    const int node = (blockIdx.x * blockDim.x + threadIdx.x) >> 6;
    const int lane = threadIdx.x & 63;
    if (node >= N_NODES) return;
    const int beg = row_ptr[node], end = row_ptr[node + 1];

    float4 a0 = make_float4(0.f, 0.f, 0.f, 0.f);
    float4 a1 = make_float4(0.f, 0.f, 0.f, 0.f);
    int j = beg;
    for (; j + 1 < end; j += 2) {
        const int s0 = col[j], s1 = col[j + 1];
        const float4 v0 = ((const float4*)(feat + (size_t)s0 * D))[lane];
        const float4 v1 = ((const float4*)(feat + (size_t)s1 * D))[lane];
        a0.x += v0.x; a0.y += v0.y; a0.z += v0.z; a0.w += v0.w;
        a1.x += v1.x; a1.y += v1.y; a1.z += v1.z; a1.w += v1.w;
    }
    if (j < end) {
        const int s0 = col[j];
        const float4 v0 = ((const float4*)(feat + (size_t)s0 * D))[lane];
        a0.x += v0.x; a0.y += v0.y; a0.z += v0.z; a0.w += v0.w;
    }
    const float invd = 1.0f / fmaxf((float)(end - beg), 1.0f);
    float4 r;
    r.x = (a0.x + a1.x) * invd;
    r.y = (a0.y + a1.y) * invd;
    r.z = (a0.z + a1.z) * invd;
    r.w = (a0.w + a1.w) * invd;
    ((float4*)(out + (size_t)node * D))[lane] = r;
}

// ---------------------------------------------------------------------------
// Fallback (tiny ws): R1 atomic scatter
// ---------------------------------------------------------------------------
__global__ __launch_bounds__(256) void scatter_kernel(
    const float* __restrict__ feat, const int* __restrict__ src,
    const int* __restrict__ dst, float* __restrict__ S, float* __restrict__ deg)
{
    const int gtid = blockIdx.x * blockDim.x + threadIdx.x;
    const int wave = gtid >> 6;
    const int lane = gtid & 63;
    const int nwaves = (gridDim.x * blockDim.x) >> 6;
    for (int e = wave; e < N_EDGES; e += nwaves) {
        const int s = src[e];
        const int d = dst[e];
        if (lane == 0) unsafeAtomicAdd(&deg[d], 1.0f);
        const float4 v = ((const float4*)(feat + (size_t)s * D))[lane];
        float* o = S + (size_t)d * D + lane * 4;
        unsafeAtomicAdd(o + 0, v.x);
        unsafeAtomicAdd(o + 1, v.y);
        unsafeAtomicAdd(o + 2, v.z);
        unsafeAtomicAdd(o + 3, v.w);
    }
}

// ---------------------------------------------------------------------------
// Fused in-place GEMM: out[i] = feat[i]@Ws^T + H[i]@Wn^T + b,
// where H = out rows (mean if !USE_DEG, else sum scaled by 1/max(deg,1)).
// Block owns BM=64 full rows -> in-place race-free.
// ---------------------------------------------------------------------------
#define BM 64
#define BK 16

template <bool USE_DEG>
__global__ __launch_bounds__(256) void fused_gemm_kernel(
    const float* __restrict__ feat,
    const float* __restrict__ w_neigh,
    const float* __restrict__ w_self,
    const float* __restrict__ b_self,
    const float* __restrict__ deg,
    float* __restrict__ out)
{
    __shared__ float At[BK][BM + 4];
    __shared__ float Bt[BK][256];

    const int tid = threadIdx.x;
    const int i0 = blockIdx.x * BM;
    const int trow = tid >> 4;
    const int tcol = tid & 15;
    const int m_load = tid >> 2;
    const int kq = tid & 3;

    const int arow = i0 + m_load;
    const bool arow_ok = arow < N_NODES;
    float invd = 1.0f;
    if (USE_DEG && arow_ok) invd = 1.0f / fmaxf(deg[arow], 1.0f);

    float acc[4][16];
#pragma unroll
    for (int r = 0; r < 4; ++r)
#pragma unroll
        for (int c = 0; c < 16; ++c) acc[r][c] = 0.0f;

    for (int kc = 0; kc < (2 * D) / BK; ++kc) {
        const int kb = kc * BK;
        const bool self_part = (kb < D);
        const int kbase = self_part ? kb : (kb - D);

        float4 va = make_float4(0.f, 0.f, 0.f, 0.f);
        if (arow_ok) {
            const float* ap = self_part ? feat : out;
            va = *(const float4*)(ap + (size_t)arow * D + kbase + kq * 4);
            if (USE_DEG && !self_part) {
                va.x *= invd; va.y *= invd; va.z *= invd; va.w *= invd;
            }
        }
        const float* W = self_part ? w_self : w_neigh;
        const float4* wp = (const float4*)(W + (size_t)tid * D + kbase);
        const float4 w0 = wp[0], w1 = wp[1], w2 = wp[2], w3 = wp[3];

        __syncthreads();
        At[kq * 4 + 0][m_load] = va.x;
        At[kq * 4 + 1][m_load] = va.y;
        At[kq * 4 + 2][m_load] = va.z;
        At[kq * 4 + 3][m_load] = va.w;
        Bt[ 0][tid] = w0.x; Bt[ 1][tid] = w0.y; Bt[ 2][tid] = w0.z; Bt[ 3][tid] = w0.w;
        Bt[ 4][tid] = w1.x; Bt[ 5][tid] = w1.y; Bt[ 6][tid] = w1.z; Bt[ 7][tid] = w1.w;
        Bt[ 8][tid] = w2.x; Bt[ 9][tid] = w2.y; Bt[10][tid] = w2.z; Bt[11][tid] = w2.w;
        Bt[12][tid] = w3.x; Bt[13][tid] = w3.y; Bt[14][tid] = w3.z; Bt[15][tid] = w3.w;
        __syncthreads();

#pragma unroll
        for (int k = 0; k < BK; ++k) {
            const float4 a = *(const float4*)&At[k][trow * 4];
            const float4 b0 = *(const float4*)&Bt[k][tcol * 16 + 0];
            const float4 b1 = *(const float4*)&Bt[k][tcol * 16 + 4];
            const float4 b2 = *(const float4*)&Bt[k][tcol * 16 + 8];
            const float4 b3 = *(const float4*)&Bt[k][tcol * 16 + 12];
            const float av[4] = {a.x, a.y, a.z, a.w};
            const float bv[16] = {b0.x, b0.y, b0.z, b0.w, b1.x, b1.y, b1.z, b1.w,
                                  b2.x, b2.y, b2.z, b2.w, b3.x, b3.y, b3.z, b3.w};
#pragma unroll
            for (int r = 0; r < 4; ++r)
#pragma unroll
                for (int c = 0; c < 16; ++c)
                    acc[r][c] = fmaf(av[r], bv[c], acc[r][c]);
        }
    }

    float4 bias[4];
#pragma unroll
    for (int c4 = 0; c4 < 4; ++c4)
        bias[c4] = *(const float4*)&b_self[tcol * 16 + c4 * 4];

#pragma unroll
    for (int r = 0; r < 4; ++r) {
        const int row = i0 + trow * 4 + r;
        if (row < N_NODES) {
            float* op = out + (size_t)row * D + tcol * 16;
#pragma unroll
            for (int c4 = 0; c4 < 4; ++c4) {
                float4 v;
                v.x = acc[r][c4 * 4 + 0] + bias[c4].x;
                v.y = acc[r][c4 * 4 + 1] + bias[c4].y;
                v.z = acc[r][c4 * 4 + 2] + bias[c4].z;
                v.w = acc[r][c4 * 4 + 3] + bias[c4].w;
                *(float4*)(op + c4 * 4) = v;
            }
        }
    }
}

// ---------------------------------------------------------------------------
extern "C" void kernel_launch(void* const* d_in, const int* in_sizes, int n_in,
                              void* d_out, int out_size, void* d_ws, size_t ws_size,
                              hipStream_t stream) {
    const float* feat    = (const float*)d_in[0];
    const int*   src     = (const int*)d_in[1];
    const int*   dst     = (const int*)d_in[2];
    const float* w_neigh = (const float*)d_in[3];
    const float* w_self  = (const float*)d_in[4];
    const float* b_self  = (const float*)d_in[5];
    float* out = (float*)d_out;

    const size_t need = (size_t)(WS_COL + N_EDGES) * sizeof(int);
    const int nblocks_gemm = (N_NODES + BM - 1) / BM;
    const int eblocks = (N_EDGES + 255) / 256;

    if (ws_size >= need) {
        int* wsI     = (int*)d_ws;
        int* counts  = wsI + WS_COUNTS;   // reused as cursor after scan
        int* row_ptr = wsI + WS_ROWPTR;
        int* col     = wsI + WS_COL;

        hipMemsetAsync(counts, 0, N_NODES * sizeof(int), stream);
        hist_kernel<<<eblocks, 256, 0, stream>>>(dst, counts);
        scan_kernel<<<1, 1024, 0, stream>>>(counts, row_ptr);
        hipMemsetAsync(counts, 0, N_NODES * sizeof(int), stream);
        fill_kernel<<<eblocks, 256, 0, stream>>>(src, dst, row_ptr, counts, col);

        const int ablocks = (N_NODES * 64 + 255) / 256;   // 1 wave/node
        aggregate_kernel<<<ablocks, 256, 0, stream>>>(feat, row_ptr, col, out);

        fused_gemm_kernel<false><<<nblocks_gemm, 256, 0, stream>>>(
            feat, w_neigh, w_self, b_self, nullptr, out);
    } else {
        float* deg = (float*)d_ws;
        hipMemsetAsync(out, 0, (size_t)N_NODES * D * sizeof(float), stream);
        hipMemsetAsync(deg, 0, (size_t)N_NODES * sizeof(float), stream);
        scatter_kernel<<<4096, 256, 0, stream>>>(feat, src, dst, out, deg);
        fused_gemm_kernel<true><<<nblocks_gemm, 256, 0, stream>>>(
            feat, w_neigh, w_self, b_self, deg, out);
    }
}

// Round 3
// 912.086 us; speedup vs baseline: 6.5154x; 1.1473x over previous
//
#include <hip/hip_runtime.h>
#include <cstddef>

#define N_NODES 100000
#define N_EDGES 1600000
#define D 256

// ---------------------------------------------------------------------------
// CSR path workspace layout (ints):
//   [0, N)            counts / cursor (reused)
//   [N, 2N+1)         row_ptr
//   [2N+16, ...)      col (N_EDGES)
// ---------------------------------------------------------------------------
#define WS_COUNTS 0
#define WS_ROWPTR (N_NODES)
#define WS_COL    (2 * N_NODES + 16)

__global__ __launch_bounds__(256) void hist_kernel(
    const int* __restrict__ dst, int* __restrict__ counts)
{
    const int i = blockIdx.x * 256 + threadIdx.x;
    if (i < N_EDGES) atomicAdd(&counts[dst[i]], 1);
}

// Single-workgroup chunked exclusive scan: row_ptr[0]=0, row_ptr[i+1]=incl sum
__global__ __launch_bounds__(1024) void scan_kernel(
    const int* __restrict__ counts, int* __restrict__ row_ptr)
{
    __shared__ int sdata[1024];
    __shared__ int s_carry;
    const int tid = threadIdx.x;
    if (tid == 0) { s_carry = 0; row_ptr[0] = 0; }
    __syncthreads();
    for (int base = 0; base < N_NODES; base += 1024) {
        const int i = base + tid;
        int v = (i < N_NODES) ? counts[i] : 0;
        sdata[tid] = v;
        __syncthreads();
        for (int off = 1; off < 1024; off <<= 1) {
            int t = (tid >= off) ? sdata[tid - off] : 0;
            __syncthreads();
            sdata[tid] += t;
            __syncthreads();
        }
        const int carry = s_carry;
        if (i < N_NODES) row_ptr[i + 1] = carry + sdata[tid];
        __syncthreads();
        if (tid == 1023) s_carry = carry + sdata[1023];
        __syncthreads();
    }
}

__global__ __launch_bounds__(256) void fill_kernel(
    const int* __restrict__ src, const int* __restrict__ dst,
    const int* __restrict__ row_ptr, int* __restrict__ cursor,
    int* __restrict__ col)
{
    const int i = blockIdx.x * 256 + threadIdx.x;
    if (i < N_EDGES) {
        const int d = dst[i];
        const int pos = atomicAdd(&cursor[d], 1);
        col[row_ptr[d] + pos] = src[i];
    }
}

// One wave per node: gather-sum neighbor rows (float4/lane = full 256-f row),
// scale by 1/max(deg,1), write the mean row once. No atomics. 4-deep MLP.
__global__ __launch_bounds__(256) void aggregate_kernel(
    const float* __restrict__ feat, const int* __restrict__ row_ptr,
    const int* __restrict__ col, float* __restrict__ out)
{
    const int node = (blockIdx.x * blockDim.x + threadIdx.x) >> 6;
    const int lane = threadIdx.x & 63;
    if (node >= N_NODES) return;
    const int beg = row_ptr[node], end = row_ptr[node + 1];

    float4 a0 = make_float4(0.f, 0.f, 0.f, 0.f);
    float4 a1 = make_float4(0.f, 0.f, 0.f, 0.f);
    float4 a2 = make_float4(0.f, 0.f, 0.f, 0.f);
    float4 a3 = make_float4(0.f, 0.f, 0.f, 0.f);
    int j = beg;
    for (; j + 3 < end; j += 4) {
        const int s0 = col[j], s1 = col[j + 1], s2 = col[j + 2], s3 = col[j + 3];
        const float4 v0 = ((const float4*)(feat + (size_t)s0 * D))[lane];
        const float4 v1 = ((const float4*)(feat + (size_t)s1 * D))[lane];
        const float4 v2 = ((const float4*)(feat + (size_t)s2 * D))[lane];
        const float4 v3 = ((const float4*)(feat + (size_t)s3 * D))[lane];
        a0.x += v0.x; a0.y += v0.y; a0.z += v0.z; a0.w += v0.w;
        a1.x += v1.x; a1.y += v1.y; a1.z += v1.z; a1.w += v1.w;
        a2.x += v2.x; a2.y += v2.y; a2.z += v2.z; a2.w += v2.w;
        a3.x += v3.x; a3.y += v3.y; a3.z += v3.z; a3.w += v3.w;
    }
    for (; j < end; ++j) {
        const int s0 = col[j];
        const float4 v0 = ((const float4*)(feat + (size_t)s0 * D))[lane];
        a0.x += v0.x; a0.y += v0.y; a0.z += v0.z; a0.w += v0.w;
    }
    const float invd = 1.0f / fmaxf((float)(end - beg), 1.0f);
    float4 r;
    r.x = ((a0.x + a1.x) + (a2.x + a3.x)) * invd;
    r.y = ((a0.y + a1.y) + (a2.y + a3.y)) * invd;
    r.z = ((a0.z + a1.z) + (a2.z + a3.z)) * invd;
    r.w = ((a0.w + a1.w) + (a2.w + a3.w)) * invd;
    ((float4*)(out + (size_t)node * D))[lane] = r;
}

// ---------------------------------------------------------------------------
// Fallback (tiny ws): R1 atomic scatter
// ---------------------------------------------------------------------------
__global__ __launch_bounds__(256) void scatter_kernel(
    const float* __restrict__ feat, const int* __restrict__ src,
    const int* __restrict__ dst, float* __restrict__ S, float* __restrict__ deg)
{
    const int gtid = blockIdx.x * blockDim.x + threadIdx.x;
    const int wave = gtid >> 6;
    const int lane = gtid & 63;
    const int nwaves = (gridDim.x * blockDim.x) >> 6;
    for (int e = wave; e < N_EDGES; e += nwaves) {
        const int s = src[e];
        const int d = dst[e];
        if (lane == 0) unsafeAtomicAdd(&deg[d], 1.0f);
        const float4 v = ((const float4*)(feat + (size_t)s * D))[lane];
        float* o = S + (size_t)d * D + lane * 4;
        unsafeAtomicAdd(o + 0, v.x);
        unsafeAtomicAdd(o + 1, v.y);
        unsafeAtomicAdd(o + 2, v.z);
        unsafeAtomicAdd(o + 3, v.w);
    }
}

// ---------------------------------------------------------------------------
// Fused in-place GEMM: out[i] = feat[i]@Ws^T + H[i]@Wn^T + b.
// Block owns BM=64 full rows (BN=256 = all cols) -> in-place race-free.
// Thread (trow=tid>>4, tcol=tid&15) computes rows trow*4+r, cols g*64+tcol*4+j
// -> Bt reads are 64-consecutive-word spans (2-way bank alias = free),
//    At reads are 4-address b128 broadcasts (conflict-free).
// ---------------------------------------------------------------------------
#define BM 64
#define BK 16

template <bool USE_DEG>
__global__ __launch_bounds__(256) void fused_gemm_kernel(
    const float* __restrict__ feat,
    const float* __restrict__ w_neigh,
    const float* __restrict__ w_self,
    const float* __restrict__ b_self,
    const float* __restrict__ deg,
    float* __restrict__ out)
{
    __shared__ float At[BK][BM + 4];
    __shared__ float Bt[BK][256];

    const int tid = threadIdx.x;
    const int i0 = blockIdx.x * BM;
    const int trow = tid >> 4;
    const int tcol = tid & 15;
    const int m_load = tid >> 2;
    const int kq = tid & 3;

    const int arow = i0 + m_load;
    const bool arow_ok = arow < N_NODES;
    float invd = 1.0f;
    if (USE_DEG && arow_ok) invd = 1.0f / fmaxf(deg[arow], 1.0f);

    float acc[4][16];
#pragma unroll
    for (int r = 0; r < 4; ++r)
#pragma unroll
        for (int c = 0; c < 16; ++c) acc[r][c] = 0.0f;

    for (int kc = 0; kc < (2 * D) / BK; ++kc) {
        const int kb = kc * BK;
        const bool self_part = (kb < D);
        const int kbase = self_part ? kb : (kb - D);

        float4 va = make_float4(0.f, 0.f, 0.f, 0.f);
        if (arow_ok) {
            const float* ap = self_part ? feat : out;
            va = *(const float4*)(ap + (size_t)arow * D + kbase + kq * 4);
            if (USE_DEG && !self_part) {
                va.x *= invd; va.y *= invd; va.z *= invd; va.w *= invd;
            }
        }
        const float* W = self_part ? w_self : w_neigh;
        const float4* wp = (const float4*)(W + (size_t)tid * D + kbase);
        const float4 w0 = wp[0], w1 = wp[1], w2 = wp[2], w3 = wp[3];

        __syncthreads();
        At[kq * 4 + 0][m_load] = va.x;
        At[kq * 4 + 1][m_load] = va.y;
        At[kq * 4 + 2][m_load] = va.z;
        At[kq * 4 + 3][m_load] = va.w;
        Bt[ 0][tid] = w0.x; Bt[ 1][tid] = w0.y; Bt[ 2][tid] = w0.z; Bt[ 3][tid] = w0.w;
        Bt[ 4][tid] = w1.x; Bt[ 5][tid] = w1.y; Bt[ 6][tid] = w1.z; Bt[ 7][tid] = w1.w;
        Bt[ 8][tid] = w2.x; Bt[ 9][tid] = w2.y; Bt[10][tid] = w2.z; Bt[11][tid] = w2.w;
        Bt[12][tid] = w3.x; Bt[13][tid] = w3.y; Bt[14][tid] = w3.z; Bt[15][tid] = w3.w;
        __syncthreads();

#pragma unroll
        for (int k = 0; k < BK; ++k) {
            const float4 a = *(const float4*)&At[k][trow * 4];
            float4 b[4];
#pragma unroll
            for (int g = 0; g < 4; ++g)
                b[g] = *(const float4*)&Bt[k][g * 64 + tcol * 4];
            const float av[4] = {a.x, a.y, a.z, a.w};
#pragma unroll
            for (int r = 0; r < 4; ++r) {
#pragma unroll
                for (int g = 0; g < 4; ++g) {
                    acc[r][g * 4 + 0] = fmaf(av[r], b[g].x, acc[r][g * 4 + 0]);
                    acc[r][g * 4 + 1] = fmaf(av[r], b[g].y, acc[r][g * 4 + 1]);
                    acc[r][g * 4 + 2] = fmaf(av[r], b[g].z, acc[r][g * 4 + 2]);
                    acc[r][g * 4 + 3] = fmaf(av[r], b[g].w, acc[r][g * 4 + 3]);
                }
            }
        }
    }

    // epilogue: bias + write. col base for group g: g*64 + tcol*4
    float4 bias[4];
#pragma unroll
    for (int g = 0; g < 4; ++g)
        bias[g] = *(const float4*)&b_self[g * 64 + tcol * 4];

#pragma unroll
    for (int r = 0; r < 4; ++r) {
        const int row = i0 + trow * 4 + r;
        if (row < N_NODES) {
            float* op = out + (size_t)row * D;
#pragma unroll
            for (int g = 0; g < 4; ++g) {
                float4 v;
                v.x = acc[r][g * 4 + 0] + bias[g].x;
                v.y = acc[r][g * 4 + 1] + bias[g].y;
                v.z = acc[r][g * 4 + 2] + bias[g].z;
                v.w = acc[r][g * 4 + 3] + bias[g].w;
                *(float4*)(op + g * 64 + tcol * 4) = v;
            }
        }
    }
}

// ---------------------------------------------------------------------------
extern "C" void kernel_launch(void* const* d_in, const int* in_sizes, int n_in,
                              void* d_out, int out_size, void* d_ws, size_t ws_size,
                              hipStream_t stream) {
    const float* feat    = (const float*)d_in[0];
    const int*   src     = (const int*)d_in[1];
    const int*   dst     = (const int*)d_in[2];
    const float* w_neigh = (const float*)d_in[3];
    const float* w_self  = (const float*)d_in[4];
    const float* b_self  = (const float*)d_in[5];
    float* out = (float*)d_out;

    const size_t need = (size_t)(WS_COL + N_EDGES) * sizeof(int);
    const int nblocks_gemm = (N_NODES + BM - 1) / BM;
    const int eblocks = (N_EDGES + 255) / 256;

    if (ws_size >= need) {
        int* wsI     = (int*)d_ws;
        int* counts  = wsI + WS_COUNTS;   // reused as cursor after scan
        int* row_ptr = wsI + WS_ROWPTR;
        int* col     = wsI + WS_COL;

        hipMemsetAsync(counts, 0, N_NODES * sizeof(int), stream);
        hist_kernel<<<eblocks, 256, 0, stream>>>(dst, counts);
        scan_kernel<<<1, 1024, 0, stream>>>(counts, row_ptr);
        hipMemsetAsync(counts, 0, N_NODES * sizeof(int), stream);
        fill_kernel<<<eblocks, 256, 0, stream>>>(src, dst, row_ptr, counts, col);

        const int ablocks = (N_NODES * 64 + 255) / 256;   // 1 wave/node
        aggregate_kernel<<<ablocks, 256, 0, stream>>>(feat, row_ptr, col, out);

        fused_gemm_kernel<false><<<nblocks_gemm, 256, 0, stream>>>(
            feat, w_neigh, w_self, b_self, nullptr, out);
    } else {
        float* deg = (float*)d_ws;
        hipMemsetAsync(out, 0, (size_t)N_NODES * D * sizeof(float), stream);
        hipMemsetAsync(deg, 0, (size_t)N_NODES * sizeof(float), stream);
        scatter_kernel<<<4096, 256, 0, stream>>>(feat, src, dst, out, deg);
        fused_gemm_kernel<true><<<nblocks_gemm, 256, 0, stream>>>(
            feat, w_neigh, w_self, b_self, deg, out);
    }
}

// Round 4
// 611.179 us; speedup vs baseline: 9.7232x; 1.4923x over previous
//
#include <hip/hip_runtime.h>
#include <cstddef>

#define N_NODES 100000
#define N_EDGES 1600000
#define D 256

typedef short  s16x8 __attribute__((ext_vector_type(8)));
typedef float  f32x4 __attribute__((ext_vector_type(4)));
typedef float  f32x8 __attribute__((ext_vector_type(8)));

__device__ __forceinline__ unsigned short f2bf(float f) {
    unsigned int u = __float_as_uint(f);
    unsigned int r = (u + 0x7fffu + ((u >> 16) & 1u)) >> 16;   // RNE
    return (unsigned short)r;
}

// ---------------------------------------------------------------------------
// Workspace layout:
//   ints:   [0,N) counts/cursor | [N,2N+1) row_ptr | [2N+16, +E) col
//           | [WS_PART, +128) scan partials
//   bytes:  WB_BYTE: weights bf16 (self 65536, neigh 65536 ushorts)
//           HB_BYTE: H bf16 (N_NODES*256 ushorts)
// ---------------------------------------------------------------------------
#define WS_COUNTS 0
#define WS_ROWPTR (N_NODES)
#define WS_COL    (2 * N_NODES + 16)
#define WS_PART   (WS_COL + N_EDGES)
#define WB_BYTE   ((size_t)(WS_PART + 128) * 4)          // 7200576, 16B-aligned
#define HB_BYTE   (WB_BYTE + 2 * 65536 * 2)              // 7462720, 16B-aligned
#define NEED_FULL (HB_BYTE + (size_t)N_NODES * D * 2)    // ~58.7 MB
#define NEED_MID  (HB_BYTE)

// ---------------------------------------------------------------------------
__global__ __launch_bounds__(256) void hist_kernel(
    const int* __restrict__ dst, int* __restrict__ counts)
{
    const int i = blockIdx.x * 256 + threadIdx.x;
    if (i < N_EDGES) atomicAdd(&counts[dst[i]], 1);
}

// ---- 3-phase scan ----------------------------------------------------------
#define SCAN_NB ((N_NODES + 1023) / 1024)   // 98

__global__ __launch_bounds__(1024) void scan_block_kernel(
    const int* __restrict__ counts, int* __restrict__ row_ptr,
    int* __restrict__ partials)
{
    __shared__ int wsum[16];
    const int t = threadIdx.x, b = blockIdx.x, i = b * 1024 + t;
    const int lane = t & 63, w = t >> 6;
    int x = (i < N_NODES) ? counts[i] : 0;
#pragma unroll
    for (int off = 1; off < 64; off <<= 1) {
        int y = __shfl_up(x, off, 64);
        if (lane >= off) x += y;
    }
    if (lane == 63) wsum[w] = x;
    __syncthreads();
    if (w == 0) {
        int s = (lane < 16) ? wsum[lane] : 0;
#pragma unroll
        for (int off = 1; off < 16; off <<= 1) {
            int y = __shfl_up(s, off, 64);
            if (lane >= off) s += y;
        }
        if (lane < 16) wsum[lane] = s;
    }
    __syncthreads();
    const int incl = x + (w > 0 ? wsum[w - 1] : 0);
    if (i < N_NODES) row_ptr[i + 1] = incl;      // block-local inclusive
    if (t == 1023) partials[b] = incl;           // block total
}

__global__ __launch_bounds__(128) void scan_partials_kernel(int* partials)
{
    __shared__ int s[128];
    const int t = threadIdx.x;
    s[t] = (t < SCAN_NB) ? partials[t] : 0;
    __syncthreads();
#pragma unroll
    for (int off = 1; off < 128; off <<= 1) {
        int y = (t >= off) ? s[t - off] : 0;
        __syncthreads();
        s[t] += y;
        __syncthreads();
    }
    if (t < SCAN_NB) partials[t] = s[t];         // inclusive partials
}

__global__ __launch_bounds__(1024) void scan_add_kernel(
    const int* __restrict__ partials, int* __restrict__ row_ptr)
{
    const int t = threadIdx.x, b = blockIdx.x, i = b * 1024 + t;
    if (i < N_NODES) {
        const int off = (b > 0) ? partials[b - 1] : 0;
        row_ptr[i + 1] += off;
    }
    if (b == 0 && t == 0) row_ptr[0] = 0;
}

__global__ __launch_bounds__(256) void fill_kernel(
    const int* __restrict__ src, const int* __restrict__ dst,
    const int* __restrict__ row_ptr, int* __restrict__ cursor,
    int* __restrict__ col)
{
    const int i = blockIdx.x * 256 + threadIdx.x;
    if (i < N_EDGES) {
        const int d = dst[i];
        const int pos = atomicAdd(&cursor[d], 1);
        col[row_ptr[d] + pos] = src[i];
    }
}

// ---- weight fp32 -> bf16 (both matrices, contiguous) -----------------------
__global__ __launch_bounds__(256) void wcvt_kernel(
    const float* __restrict__ w_self, const float* __restrict__ w_neigh,
    unsigned short* __restrict__ wb)
{
    const int i = blockIdx.x * 256 + threadIdx.x;      // 0..32767, 4 elems each
    const bool isself = (i < 16384);
    const float* srcp = isself ? w_self : w_neigh;
    const int j = (isself ? i : i - 16384) * 4;
    const float4 v = *(const float4*)(srcp + j);
    ushort4 o;
    o.x = f2bf(v.x); o.y = f2bf(v.y); o.z = f2bf(v.z); o.w = f2bf(v.w);
    ((ushort4*)wb)[i] = o;
}

// ---- pull-mode aggregation: one wave per node ------------------------------
template <bool BF16OUT>
__global__ __launch_bounds__(256) void aggregate_kernel(
    const float* __restrict__ feat, const int* __restrict__ row_ptr,
    const int* __restrict__ col, float* __restrict__ outf,
    unsigned short* __restrict__ outb)
{
    const int node = (blockIdx.x * blockDim.x + threadIdx.x) >> 6;
    const int lane = threadIdx.x & 63;
    if (node >= N_NODES) return;
    const int beg = row_ptr[node], end = row_ptr[node + 1];

    float4 a0 = make_float4(0.f, 0.f, 0.f, 0.f);
    float4 a1 = make_float4(0.f, 0.f, 0.f, 0.f);
    float4 a2 = make_float4(0.f, 0.f, 0.f, 0.f);
    float4 a3 = make_float4(0.f, 0.f, 0.f, 0.f);
    int j = beg;
    for (; j + 3 < end; j += 4) {
        const int s0 = col[j], s1 = col[j + 1], s2 = col[j + 2], s3 = col[j + 3];
        const float4 v0 = ((const float4*)(feat + (size_t)s0 * D))[lane];
        const float4 v1 = ((const float4*)(feat + (size_t)s1 * D))[lane];
        const float4 v2 = ((const float4*)(feat + (size_t)s2 * D))[lane];
        const float4 v3 = ((const float4*)(feat + (size_t)s3 * D))[lane];
        a0.x += v0.x; a0.y += v0.y; a0.z += v0.z; a0.w += v0.w;
        a1.x += v1.x; a1.y += v1.y; a1.z += v1.z; a1.w += v1.w;
        a2.x += v2.x; a2.y += v2.y; a2.z += v2.z; a2.w += v2.w;
        a3.x += v3.x; a3.y += v3.y; a3.z += v3.z; a3.w += v3.w;
    }
    for (; j < end; ++j) {
        const int s0 = col[j];
        const float4 v0 = ((const float4*)(feat + (size_t)s0 * D))[lane];
        a0.x += v0.x; a0.y += v0.y; a0.z += v0.z; a0.w += v0.w;
    }
    const float invd = 1.0f / fmaxf((float)(end - beg), 1.0f);
    float4 r;
    r.x = ((a0.x + a1.x) + (a2.x + a3.x)) * invd;
    r.y = ((a0.y + a1.y) + (a2.y + a3.y)) * invd;
    r.z = ((a0.z + a1.z) + (a2.z + a3.z)) * invd;
    r.w = ((a0.w + a1.w) + (a2.w + a3.w)) * invd;
    if (BF16OUT) {
        ushort4 o;
        o.x = f2bf(r.x); o.y = f2bf(r.y); o.z = f2bf(r.z); o.w = f2bf(r.w);
        ((ushort4*)(outb + (size_t)node * D))[lane] = o;
    } else {
        ((float4*)(outf + (size_t)node * D))[lane] = r;
    }
}

// ---------------------------------------------------------------------------
// MFMA GEMM: out[i] = feat[i]@Ws^T + H[i]@Wn^T + b.  One wave per 16 rows,
// all 256 cols.  No LDS, no barriers: A frags from global (row=lane&15,
// k=(lane>>4)*8+i), B frags from bf16 weights ([N][K] row-major == B^T frag
// layout), C/D col=lane&15, row=(lane>>4)*4+reg.
// HBF16: H read as bf16 from ws; else fp32 from out (in-place, own rows only).
// ---------------------------------------------------------------------------
template <bool HBF16>
__global__ __launch_bounds__(256) void gemm_mfma_kernel(
    const float* __restrict__ feat,
    const unsigned short* __restrict__ wb,     // self @0, neigh @+65536
    const float* __restrict__ b_self,
    const unsigned short* __restrict__ hb,
    const float* h32,                          // may alias outp
    float* outp)
{
    const int wid = (blockIdx.x * blockDim.x + threadIdx.x) >> 6;
    const int lane = threadIdx.x & 63;
    if (wid >= N_NODES / 16) return;
    const int nl = lane & 15;
    const int kg = lane >> 4;
    const int row0 = wid * 16;

    f32x4 acc[16];
#pragma unroll
    for (int n = 0; n < 16; ++n) acc[n] = (f32x4){0.f, 0.f, 0.f, 0.f};

    const float* af = feat + (size_t)(row0 + nl) * D + kg * 8;
    const unsigned short* hbrow =
        HBF16 ? (hb + (size_t)(row0 + nl) * D + kg * 8) : nullptr;
    const float* h32row =
        HBF16 ? nullptr : (h32 + (size_t)(row0 + nl) * D + kg * 8);

#pragma unroll
    for (int half = 0; half < 2; ++half) {
        const unsigned short* wh = wb + half * 65536 + nl * 256 + kg * 8;
#pragma unroll 2
        for (int kk = 0; kk < 8; ++kk) {
            const int kb = kk * 32;
            s16x8 afrag;
            if (half == 0) {
                const f32x8 av = *(const f32x8*)(af + kb);
#pragma unroll
                for (int i = 0; i < 8; ++i) afrag[i] = (short)f2bf(av[i]);
            } else if (HBF16) {
                afrag = *(const s16x8*)(hbrow + kb);
            } else {
                const f32x8 av = *(const f32x8*)(h32row + kb);
#pragma unroll
                for (int i = 0; i < 8; ++i) afrag[i] = (short)f2bf(av[i]);
            }
#pragma unroll
            for (int n = 0; n < 16; ++n) {
                const s16x8 bfrag = *(const s16x8*)(wh + n * 4096 + kb);
                acc[n] = __builtin_amdgcn_mfma_f32_16x16x32_bf16(
                    afrag, bfrag, acc[n], 0, 0, 0);
            }
        }
    }

#pragma unroll
    for (int n = 0; n < 16; ++n) {
        const float bias = b_self[n * 16 + nl];
        float* op = outp + (size_t)(row0 + kg * 4) * D + n * 16 + nl;
#pragma unroll
        for (int r = 0; r < 4; ++r)
            op[(size_t)r * D] = acc[n][r] + bias;
    }
}

// ---------------------------------------------------------------------------
// Atomic fallback path (tiny ws): R1 scatter + fp32 GEMM
// ---------------------------------------------------------------------------
__global__ __launch_bounds__(256) void scatter_kernel(
    const float* __restrict__ feat, const int* __restrict__ src,
    const int* __restrict__ dst, float* __restrict__ S, float* __restrict__ deg)
{
    const int gtid = blockIdx.x * blockDim.x + threadIdx.x;
    const int wave = gtid >> 6;
    const int lane = gtid & 63;
    const int nwaves = (gridDim.x * blockDim.x) >> 6;
    for (int e = wave; e < N_EDGES; e += nwaves) {
        const int s = src[e];
        const int d = dst[e];
        if (lane == 0) unsafeAtomicAdd(&deg[d], 1.0f);
        const float4 v = ((const float4*)(feat + (size_t)s * D))[lane];
        float* o = S + (size_t)d * D + lane * 4;
        unsafeAtomicAdd(o + 0, v.x);
        unsafeAtomicAdd(o + 1, v.y);
        unsafeAtomicAdd(o + 2, v.z);
        unsafeAtomicAdd(o + 3, v.w);
    }
}

#define BM 64
#define BK 16

__global__ __launch_bounds__(256) void fused_gemm_f32(
    const float* __restrict__ feat, const float* __restrict__ w_neigh,
    const float* __restrict__ w_self, const float* __restrict__ b_self,
    const float* __restrict__ deg, float* out)
{
    __shared__ float At[BK][BM + 4];
    __shared__ float Bt[BK][256];

    const int tid = threadIdx.x;
    const int i0 = blockIdx.x * BM;
    const int trow = tid >> 4;
    const int tcol = tid & 15;
    const int m_load = tid >> 2;
    const int kq = tid & 3;

    const int arow = i0 + m_load;
    const bool arow_ok = arow < N_NODES;
    float invd = 1.0f;
    if (arow_ok) invd = 1.0f / fmaxf(deg[arow], 1.0f);

    float acc[4][16];
#pragma unroll
    for (int r = 0; r < 4; ++r)
#pragma unroll
        for (int c = 0; c < 16; ++c) acc[r][c] = 0.0f;

    for (int kc = 0; kc < (2 * D) / BK; ++kc) {
        const int kb = kc * BK;
        const bool self_part = (kb < D);
        const int kbase = self_part ? kb : (kb - D);

        float4 va = make_float4(0.f, 0.f, 0.f, 0.f);
        if (arow_ok) {
            const float* ap = self_part ? feat : out;
            va = *(const float4*)(ap + (size_t)arow * D + kbase + kq * 4);
            if (!self_part) { va.x *= invd; va.y *= invd; va.z *= invd; va.w *= invd; }
        }
        const float* W = self_part ? w_self : w_neigh;
        const float4* wp = (const float4*)(W + (size_t)tid * D + kbase);
        const float4 w0 = wp[0], w1 = wp[1], w2 = wp[2], w3 = wp[3];

        __syncthreads();
        At[kq * 4 + 0][m_load] = va.x;
        At[kq * 4 + 1][m_load] = va.y;
        At[kq * 4 + 2][m_load] = va.z;
        At[kq * 4 + 3][m_load] = va.w;
        Bt[ 0][tid] = w0.x; Bt[ 1][tid] = w0.y; Bt[ 2][tid] = w0.z; Bt[ 3][tid] = w0.w;
        Bt[ 4][tid] = w1.x; Bt[ 5][tid] = w1.y; Bt[ 6][tid] = w1.z; Bt[ 7][tid] = w1.w;
        Bt[ 8][tid] = w2.x; Bt[ 9][tid] = w2.y; Bt[10][tid] = w2.z; Bt[11][tid] = w2.w;
        Bt[12][tid] = w3.x; Bt[13][tid] = w3.y; Bt[14][tid] = w3.z; Bt[15][tid] = w3.w;
        __syncthreads();

#pragma unroll
        for (int k = 0; k < BK; ++k) {
            const float4 a = *(const float4*)&At[k][trow * 4];
            float4 b[4];
#pragma unroll
            for (int g = 0; g < 4; ++g)
                b[g] = *(const float4*)&Bt[k][g * 64 + tcol * 4];
            const float av[4] = {a.x, a.y, a.z, a.w};
#pragma unroll
            for (int r = 0; r < 4; ++r)
#pragma unroll
                for (int g = 0; g < 4; ++g) {
                    acc[r][g * 4 + 0] = fmaf(av[r], b[g].x, acc[r][g * 4 + 0]);
                    acc[r][g * 4 + 1] = fmaf(av[r], b[g].y, acc[r][g * 4 + 1]);
                    acc[r][g * 4 + 2] = fmaf(av[r], b[g].z, acc[r][g * 4 + 2]);
                    acc[r][g * 4 + 3] = fmaf(av[r], b[g].w, acc[r][g * 4 + 3]);
                }
        }
    }

    float4 bias[4];
#pragma unroll
    for (int g = 0; g < 4; ++g)
        bias[g] = *(const float4*)&b_self[g * 64 + tcol * 4];

#pragma unroll
    for (int r = 0; r < 4; ++r) {
        const int row = i0 + trow * 4 + r;
        if (row < N_NODES) {
            float* op = out + (size_t)row * D;
#pragma unroll
            for (int g = 0; g < 4; ++g) {
                float4 v;
                v.x = acc[r][g * 4 + 0] + bias[g].x;
                v.y = acc[r][g * 4 + 1] + bias[g].y;
                v.z = acc[r][g * 4 + 2] + bias[g].z;
                v.w = acc[r][g * 4 + 3] + bias[g].w;
                *(float4*)(op + g * 64 + tcol * 4) = v;
            }
        }
    }
}

// ---------------------------------------------------------------------------
extern "C" void kernel_launch(void* const* d_in, const int* in_sizes, int n_in,
                              void* d_out, int out_size, void* d_ws, size_t ws_size,
                              hipStream_t stream) {
    const float* feat    = (const float*)d_in[0];
    const int*   src     = (const int*)d_in[1];
    const int*   dst     = (const int*)d_in[2];
    const float* w_neigh = (const float*)d_in[3];
    const float* w_self  = (const float*)d_in[4];
    const float* b_self  = (const float*)d_in[5];
    float* out = (float*)d_out;

    const int eblocks = (N_EDGES + 255) / 256;
    const int ablocks = (N_NODES * 64 + 255) / 256;        // 1 wave/node
    const int gblocks = (N_NODES / 16 + 3) / 4;            // 1 wave/16 rows

    if (ws_size >= NEED_MID) {
        int* wsI     = (int*)d_ws;
        int* counts  = wsI + WS_COUNTS;
        int* row_ptr = wsI + WS_ROWPTR;
        int* col     = wsI + WS_COL;
        int* part    = wsI + WS_PART;
        unsigned short* wb = (unsigned short*)((char*)d_ws + WB_BYTE);
        unsigned short* hb = (unsigned short*)((char*)d_ws + HB_BYTE);

        hipMemsetAsync(counts, 0, N_NODES * sizeof(int), stream);
        hist_kernel<<<eblocks, 256, 0, stream>>>(dst, counts);
        scan_block_kernel<<<SCAN_NB, 1024, 0, stream>>>(counts, row_ptr, part);
        scan_partials_kernel<<<1, 128, 0, stream>>>(part);
        scan_add_kernel<<<SCAN_NB, 1024, 0, stream>>>(part, row_ptr);
        hipMemsetAsync(counts, 0, N_NODES * sizeof(int), stream);
        fill_kernel<<<eblocks, 256, 0, stream>>>(src, dst, row_ptr, counts, col);
        wcvt_kernel<<<128, 256, 0, stream>>>(w_self, w_neigh, wb);

        if (ws_size >= NEED_FULL) {
            aggregate_kernel<true><<<ablocks, 256, 0, stream>>>(
                feat, row_ptr, col, nullptr, hb);
            gemm_mfma_kernel<true><<<gblocks, 256, 0, stream>>>(
                feat, wb, b_self, hb, nullptr, out);
        } else {
            aggregate_kernel<false><<<ablocks, 256, 0, stream>>>(
                feat, row_ptr, col, out, nullptr);
            gemm_mfma_kernel<false><<<gblocks, 256, 0, stream>>>(
                feat, wb, b_self, nullptr, out, out);
        }
    } else {
        float* deg = (float*)d_ws;
        hipMemsetAsync(out, 0, (size_t)N_NODES * D * sizeof(float), stream);
        hipMemsetAsync(deg, 0, (size_t)N_NODES * sizeof(float), stream);
        scatter_kernel<<<4096, 256, 0, stream>>>(feat, src, dst, out, deg);
        fused_gemm_f32<<<(N_NODES + BM - 1) / BM, 256, 0, stream>>>(
            feat, w_neigh, w_self, b_self, deg, out);
    }
}

// Round 5
// 540.585 us; speedup vs baseline: 10.9929x; 1.1306x over previous
//
#include <hip/hip_runtime.h>
#include <cstddef>

#define N_NODES 100000
#define N_EDGES 1600000
#define D 256

typedef short  s16x8 __attribute__((ext_vector_type(8)));
typedef float  f32x4 __attribute__((ext_vector_type(4)));
typedef float  f32x8 __attribute__((ext_vector_type(8)));

__device__ __forceinline__ unsigned short f2bf(float f) {
    unsigned int u = __float_as_uint(f);
    unsigned int r = (u + 0x7fffu + ((u >> 16) & 1u)) >> 16;   // RNE
    return (unsigned short)r;
}
__device__ __forceinline__ float bf2f(unsigned short u) {
    return __uint_as_float(((unsigned int)u) << 16);
}

// ---------------------------------------------------------------------------
// Workspace layout:
//   ints:  [0,N) counts/cursor | [N,2N+1) row_ptr | [2N+16,+E) col | +128 part
//   bytes: WB_BYTE  weights bf16 (self 65536, neigh 65536 ushorts)
//          FB_BYTE  feat bf16 (N*256 ushorts)                  [LARGE & XL]
//          HB2_BYTE H bf16   (N*256 ushorts)                   [XL only]
// ---------------------------------------------------------------------------
#define WS_COUNTS 0
#define WS_ROWPTR (N_NODES)
#define WS_COL    (2 * N_NODES + 16)
#define WS_PART   (WS_COL + N_EDGES)
#define WB_BYTE   ((size_t)(WS_PART + 128) * 4)            // 7,200,576
#define FB_BYTE   (WB_BYTE + 2 * 65536 * 2)                // 7,462,720
#define FB_SZ     ((size_t)N_NODES * D * 2)                // 51,200,000
#define HB2_BYTE  (FB_BYTE + FB_SZ)
#define NEED_LARGE (FB_BYTE + FB_SZ)                       // 58.66 MB (== R4 FULL)
#define NEED_XL    (HB2_BYTE + FB_SZ)                      // 109.9 MB
#define NEED_MID   (FB_BYTE)                               // 7.46 MB

// ---------------------------------------------------------------------------
__global__ __launch_bounds__(256) void hist_kernel(
    const int* __restrict__ dst, int* __restrict__ counts)
{
    const int i = blockIdx.x * 256 + threadIdx.x;
    if (i < N_EDGES) atomicAdd(&counts[dst[i]], 1);
}

// ---- 3-phase scan ----------------------------------------------------------
#define SCAN_NB ((N_NODES + 1023) / 1024)   // 98

__global__ __launch_bounds__(1024) void scan_block_kernel(
    const int* __restrict__ counts, int* __restrict__ row_ptr,
    int* __restrict__ partials)
{
    __shared__ int wsum[16];
    const int t = threadIdx.x, b = blockIdx.x, i = b * 1024 + t;
    const int lane = t & 63, w = t >> 6;
    int x = (i < N_NODES) ? counts[i] : 0;
#pragma unroll
    for (int off = 1; off < 64; off <<= 1) {
        int y = __shfl_up(x, off, 64);
        if (lane >= off) x += y;
    }
    if (lane == 63) wsum[w] = x;
    __syncthreads();
    if (w == 0) {
        int s = (lane < 16) ? wsum[lane] : 0;
#pragma unroll
        for (int off = 1; off < 16; off <<= 1) {
            int y = __shfl_up(s, off, 64);
            if (lane >= off) s += y;
        }
        if (lane < 16) wsum[lane] = s;
    }
    __syncthreads();
    const int incl = x + (w > 0 ? wsum[w - 1] : 0);
    if (i < N_NODES) row_ptr[i + 1] = incl;
    if (t == 1023) partials[b] = incl;
}

__global__ __launch_bounds__(128) void scan_partials_kernel(int* partials)
{
    __shared__ int s[128];
    const int t = threadIdx.x;
    s[t] = (t < SCAN_NB) ? partials[t] : 0;
    __syncthreads();
#pragma unroll
    for (int off = 1; off < 128; off <<= 1) {
        int y = (t >= off) ? s[t - off] : 0;
        __syncthreads();
        s[t] += y;
        __syncthreads();
    }
    if (t < SCAN_NB) partials[t] = s[t];
}

__global__ __launch_bounds__(1024) void scan_add_kernel(
    const int* __restrict__ partials, int* __restrict__ row_ptr)
{
    const int t = threadIdx.x, b = blockIdx.x, i = b * 1024 + t;
    if (i < N_NODES) {
        const int off = (b > 0) ? partials[b - 1] : 0;
        row_ptr[i + 1] += off;
    }
    if (b == 0 && t == 0) row_ptr[0] = 0;
}

__global__ __launch_bounds__(256) void fill_kernel(
    const int* __restrict__ src, const int* __restrict__ dst,
    const int* __restrict__ row_ptr, int* __restrict__ cursor,
    int* __restrict__ col)
{
    const int i = blockIdx.x * 256 + threadIdx.x;
    if (i < N_EDGES) {
        const int d = dst[i];
        const int pos = atomicAdd(&cursor[d], 1);
        col[row_ptr[d] + pos] = src[i];
    }
}

// ---- weight fp32 -> bf16 ---------------------------------------------------
__global__ __launch_bounds__(256) void wcvt_kernel(
    const float* __restrict__ w_self, const float* __restrict__ w_neigh,
    unsigned short* __restrict__ wb)
{
    const int i = blockIdx.x * 256 + threadIdx.x;      // 0..32767, 4 elems each
    const bool isself = (i < 16384);
    const float* srcp = isself ? w_self : w_neigh;
    const int j = (isself ? i : i - 16384) * 4;
    const float4 v = *(const float4*)(srcp + j);
    ushort4 o;
    o.x = f2bf(v.x); o.y = f2bf(v.y); o.z = f2bf(v.z); o.w = f2bf(v.w);
    ((ushort4*)wb)[i] = o;
}

// ---- feat fp32 -> bf16 (8 elems/thread) ------------------------------------
__global__ __launch_bounds__(256) void fcvt_kernel(
    const float* __restrict__ feat, unsigned short* __restrict__ fb)
{
    const int i = blockIdx.x * 256 + threadIdx.x;      // 8 elems each
    const f32x8 v = ((const f32x8*)feat)[i];
    ushort4 a, b;
    a.x = f2bf(v[0]); a.y = f2bf(v[1]); a.z = f2bf(v[2]); a.w = f2bf(v[3]);
    b.x = f2bf(v[4]); b.y = f2bf(v[5]); b.z = f2bf(v[6]); b.w = f2bf(v[7]);
    ((ushort4*)fb)[i * 2 + 0] = a;
    ((ushort4*)fb)[i * 2 + 1] = b;
}

// ---- pull-mode aggregation: one wave per node ------------------------------
// INBF16: gather 512B bf16 rows (ushort4/lane); else 1KB fp32 (float4/lane).
// OUTBF16: write H bf16 to outb; else fp32 to outf.
template <bool INBF16, bool OUTBF16>
__global__ __launch_bounds__(256) void aggregate_kernel(
    const float* __restrict__ feat, const unsigned short* __restrict__ featb,
    const int* __restrict__ row_ptr, const int* __restrict__ col,
    float* __restrict__ outf, unsigned short* __restrict__ outb)
{
    const int node = (blockIdx.x * blockDim.x + threadIdx.x) >> 6;
    const int lane = threadIdx.x & 63;
    if (node >= N_NODES) return;
    const int beg = row_ptr[node], end = row_ptr[node + 1];

    float4 a0 = make_float4(0.f, 0.f, 0.f, 0.f);
    float4 a1 = make_float4(0.f, 0.f, 0.f, 0.f);
    float4 a2 = make_float4(0.f, 0.f, 0.f, 0.f);
    float4 a3 = make_float4(0.f, 0.f, 0.f, 0.f);

#define ACC(acc, s)                                                          \
    do {                                                                     \
        if (INBF16) {                                                        \
            const ushort4 u = ((const ushort4*)(featb + (size_t)(s) * D))[lane]; \
            acc.x += bf2f(u.x); acc.y += bf2f(u.y);                          \
            acc.z += bf2f(u.z); acc.w += bf2f(u.w);                          \
        } else {                                                             \
            const float4 v = ((const float4*)(feat + (size_t)(s) * D))[lane];\
            acc.x += v.x; acc.y += v.y; acc.z += v.z; acc.w += v.w;          \
        }                                                                    \
    } while (0)

    int j = beg;
    for (; j + 3 < end; j += 4) {
        const int s0 = col[j], s1 = col[j + 1], s2 = col[j + 2], s3 = col[j + 3];
        ACC(a0, s0); ACC(a1, s1); ACC(a2, s2); ACC(a3, s3);
    }
    for (; j < end; ++j) { const int s0 = col[j]; ACC(a0, s0); }
#undef ACC

    const float invd = 1.0f / fmaxf((float)(end - beg), 1.0f);
    float4 r;
    r.x = ((a0.x + a1.x) + (a2.x + a3.x)) * invd;
    r.y = ((a0.y + a1.y) + (a2.y + a3.y)) * invd;
    r.z = ((a0.z + a1.z) + (a2.z + a3.z)) * invd;
    r.w = ((a0.w + a1.w) + (a2.w + a3.w)) * invd;
    if (OUTBF16) {
        ushort4 o;
        o.x = f2bf(r.x); o.y = f2bf(r.y); o.z = f2bf(r.z); o.w = f2bf(r.w);
        ((ushort4*)(outb + (size_t)node * D))[lane] = o;
    } else {
        ((float4*)(outf + (size_t)node * D))[lane] = r;
    }
}

// ---------------------------------------------------------------------------
// MFMA GEMM: out[i] = feat[i]@Ws^T + H[i]@Wn^T + b.  One wave per 16 rows,
// all 256 cols.  No LDS/barriers.  A frag: row=lane&15, k=(lane>>4)*8+i.
// B frag from bf16 weights ([N][K] row-major == B^T frag layout).
// C/D: col=lane&15, row=(lane>>4)*4+reg.
// ABF16: self-part A from featb (bf16) else feat (fp32, cvt).
// HBF16: neigh-part A from hb (bf16) else h32 (fp32, cvt; may alias outp:
//        each wave reads only the 16 rows it later writes -> race-free).
// ---------------------------------------------------------------------------
template <bool ABF16, bool HBF16>
__global__ __launch_bounds__(256) void gemm_mfma_kernel(
    const float* __restrict__ feat, const unsigned short* __restrict__ featb,
    const unsigned short* __restrict__ wb,     // self @0, neigh @+65536
    const float* __restrict__ b_self,
    const unsigned short* __restrict__ hb, const float* h32,
    float* outp)
{
    const int wid = (blockIdx.x * blockDim.x + threadIdx.x) >> 6;
    const int lane = threadIdx.x & 63;
    if (wid >= N_NODES / 16) return;
    const int nl = lane & 15;
    const int kg = lane >> 4;
    const int row0 = wid * 16;

    f32x4 acc[16];
#pragma unroll
    for (int n = 0; n < 16; ++n) acc[n] = (f32x4){0.f, 0.f, 0.f, 0.f};

    const size_t rowoff = (size_t)(row0 + nl) * D + kg * 8;
    const float*          af  = feat  + rowoff;
    const unsigned short* afb = ABF16 ? (featb + rowoff) : nullptr;
    const unsigned short* hbr = HBF16 ? (hb + rowoff) : nullptr;
    const float*          h3r = HBF16 ? nullptr : (h32 + rowoff);

#pragma unroll
    for (int half = 0; half < 2; ++half) {
        const unsigned short* wh = wb + half * 65536 + nl * 256 + kg * 8;
#pragma unroll 2
        for (int kk = 0; kk < 8; ++kk) {
            const int kb = kk * 32;
            s16x8 afrag;
            if (half == 0) {
                if (ABF16) {
                    afrag = *(const s16x8*)(afb + kb);
                } else {
                    const f32x8 av = *(const f32x8*)(af + kb);
#pragma unroll
                    for (int i = 0; i < 8; ++i) afrag[i] = (short)f2bf(av[i]);
                }
            } else if (HBF16) {
                afrag = *(const s16x8*)(hbr + kb);
            } else {
                const f32x8 av = *(const f32x8*)(h3r + kb);
#pragma unroll
                for (int i = 0; i < 8; ++i) afrag[i] = (short)f2bf(av[i]);
            }
#pragma unroll
            for (int n = 0; n < 16; ++n) {
                const s16x8 bfrag = *(const s16x8*)(wh + n * 4096 + kb);
                acc[n] = __builtin_amdgcn_mfma_f32_16x16x32_bf16(
                    afrag, bfrag, acc[n], 0, 0, 0);
            }
        }
    }

#pragma unroll
    for (int n = 0; n < 16; ++n) {
        const float bias = b_self[n * 16 + nl];
        float* op = outp + (size_t)(row0 + kg * 4) * D + n * 16 + nl;
#pragma unroll
        for (int r = 0; r < 4; ++r)
            op[(size_t)r * D] = acc[n][r] + bias;
    }
}

// ---------------------------------------------------------------------------
// Atomic fallback path (tiny ws)
// ---------------------------------------------------------------------------
__global__ __launch_bounds__(256) void scatter_kernel(
    const float* __restrict__ feat, const int* __restrict__ src,
    const int* __restrict__ dst, float* __restrict__ S, float* __restrict__ deg)
{
    const int gtid = blockIdx.x * blockDim.x + threadIdx.x;
    const int wave = gtid >> 6;
    const int lane = gtid & 63;
    const int nwaves = (gridDim.x * blockDim.x) >> 6;
    for (int e = wave; e < N_EDGES; e += nwaves) {
        const int s = src[e];
        const int d = dst[e];
        if (lane == 0) unsafeAtomicAdd(&deg[d], 1.0f);
        const float4 v = ((const float4*)(feat + (size_t)s * D))[lane];
        float* o = S + (size_t)d * D + lane * 4;
        unsafeAtomicAdd(o + 0, v.x);
        unsafeAtomicAdd(o + 1, v.y);
        unsafeAtomicAdd(o + 2, v.z);
        unsafeAtomicAdd(o + 3, v.w);
    }
}

#define BM 64
#define BK 16

__global__ __launch_bounds__(256) void fused_gemm_f32(
    const float* __restrict__ feat, const float* __restrict__ w_neigh,
    const float* __restrict__ w_self, const float* __restrict__ b_self,
    const float* __restrict__ deg, float* out)
{
    __shared__ float At[BK][BM + 4];
    __shared__ float Bt[BK][256];

    const int tid = threadIdx.x;
    const int i0 = blockIdx.x * BM;
    const int trow = tid >> 4;
    const int tcol = tid & 15;
    const int m_load = tid >> 2;
    const int kq = tid & 3;

    const int arow = i0 + m_load;
    const bool arow_ok = arow < N_NODES;
    float invd = 1.0f;
    if (arow_ok) invd = 1.0f / fmaxf(deg[arow], 1.0f);

    float acc[4][16];
#pragma unroll
    for (int r = 0; r < 4; ++r)
#pragma unroll
        for (int c = 0; c < 16; ++c) acc[r][c] = 0.0f;

    for (int kc = 0; kc < (2 * D) / BK; ++kc) {
        const int kb = kc * BK;
        const bool self_part = (kb < D);
        const int kbase = self_part ? kb : (kb - D);

        float4 va = make_float4(0.f, 0.f, 0.f, 0.f);
        if (arow_ok) {
            const float* ap = self_part ? feat : out;
            va = *(const float4*)(ap + (size_t)arow * D + kbase + kq * 4);
            if (!self_part) { va.x *= invd; va.y *= invd; va.z *= invd; va.w *= invd; }
        }
        const float* W = self_part ? w_self : w_neigh;
        const float4* wp = (const float4*)(W + (size_t)tid * D + kbase);
        const float4 w0 = wp[0], w1 = wp[1], w2 = wp[2], w3 = wp[3];

        __syncthreads();
        At[kq * 4 + 0][m_load] = va.x;
        At[kq * 4 + 1][m_load] = va.y;
        At[kq * 4 + 2][m_load] = va.z;
        At[kq * 4 + 3][m_load] = va.w;
        Bt[ 0][tid] = w0.x; Bt[ 1][tid] = w0.y; Bt[ 2][tid] = w0.z; Bt[ 3][tid] = w0.w;
        Bt[ 4][tid] = w1.x; Bt[ 5][tid] = w1.y; Bt[ 6][tid] = w1.z; Bt[ 7][tid] = w1.w;
        Bt[ 8][tid] = w2.x; Bt[ 9][tid] = w2.y; Bt[10][tid] = w2.z; Bt[11][tid] = w2.w;
        Bt[12][tid] = w3.x; Bt[13][tid] = w3.y; Bt[14][tid] = w3.z; Bt[15][tid] = w3.w;
        __syncthreads();

#pragma unroll
        for (int k = 0; k < BK; ++k) {
            const float4 a = *(const float4*)&At[k][trow * 4];
            float4 b[4];
#pragma unroll
            for (int g = 0; g < 4; ++g)
                b[g] = *(const float4*)&Bt[k][g * 64 + tcol * 4];
            const float av[4] = {a.x, a.y, a.z, a.w};
#pragma unroll
            for (int r = 0; r < 4; ++r)
#pragma unroll
                for (int g = 0; g < 4; ++g) {
                    acc[r][g * 4 + 0] = fmaf(av[r], b[g].x, acc[r][g * 4 + 0]);
                    acc[r][g * 4 + 1] = fmaf(av[r], b[g].y, acc[r][g * 4 + 1]);
                    acc[r][g * 4 + 2] = fmaf(av[r], b[g].z, acc[r][g * 4 + 2]);
                    acc[r][g * 4 + 3] = fmaf(av[r], b[g].w, acc[r][g * 4 + 3]);
                }
        }
    }

    float4 bias[4];
#pragma unroll
    for (int g = 0; g < 4; ++g)
        bias[g] = *(const float4*)&b_self[g * 64 + tcol * 4];

#pragma unroll
    for (int r = 0; r < 4; ++r) {
        const int row = i0 + trow * 4 + r;
        if (row < N_NODES) {
            float* op = out + (size_t)row * D;
#pragma unroll
            for (int g = 0; g < 4; ++g) {
                float4 v;
                v.x = acc[r][g * 4 + 0] + bias[g].x;
                v.y = acc[r][g * 4 + 1] + bias[g].y;
                v.z = acc[r][g * 4 + 2] + bias[g].z;
                v.w = acc[r][g * 4 + 3] + bias[g].w;
                *(float4*)(op + g * 64 + tcol * 4) = v;
            }
        }
    }
}

// ---------------------------------------------------------------------------
extern "C" void kernel_launch(void* const* d_in, const int* in_sizes, int n_in,
                              void* d_out, int out_size, void* d_ws, size_t ws_size,
                              hipStream_t stream) {
    const float* feat    = (const float*)d_in[0];
    const int*   src     = (const int*)d_in[1];
    const int*   dst     = (const int*)d_in[2];
    const float* w_neigh = (const float*)d_in[3];
    const float* w_self  = (const float*)d_in[4];
    const float* b_self  = (const float*)d_in[5];
    float* out = (float*)d_out;

    const int eblocks = (N_EDGES + 255) / 256;
    const int ablocks = (N_NODES * 64 + 255) / 256;        // 1 wave/node
    const int gblocks = (N_NODES / 16 + 3) / 4;            // 1 wave/16 rows
    const int fblocks = (N_NODES * D / 8 + 255) / 256;     // fcvt

    if (ws_size >= NEED_MID) {
        int* wsI     = (int*)d_ws;
        int* counts  = wsI + WS_COUNTS;
        int* row_ptr = wsI + WS_ROWPTR;
        int* col     = wsI + WS_COL;
        int* part    = wsI + WS_PART;
        unsigned short* wb = (unsigned short*)((char*)d_ws + WB_BYTE);
        unsigned short* fb = (unsigned short*)((char*)d_ws + FB_BYTE);
        unsigned short* hb = (unsigned short*)((char*)d_ws + HB2_BYTE);

        hipMemsetAsync(counts, 0, N_NODES * sizeof(int), stream);
        hist_kernel<<<eblocks, 256, 0, stream>>>(dst, counts);
        scan_block_kernel<<<SCAN_NB, 1024, 0, stream>>>(counts, row_ptr, part);
        scan_partials_kernel<<<1, 128, 0, stream>>>(part);
        scan_add_kernel<<<SCAN_NB, 1024, 0, stream>>>(part, row_ptr);
        hipMemsetAsync(counts, 0, N_NODES * sizeof(int), stream);
        fill_kernel<<<eblocks, 256, 0, stream>>>(src, dst, row_ptr, counts, col);
        wcvt_kernel<<<128, 256, 0, stream>>>(w_self, w_neigh, wb);

        if (ws_size >= NEED_XL) {
            fcvt_kernel<<<fblocks, 256, 0, stream>>>(feat, fb);
            aggregate_kernel<true, true><<<ablocks, 256, 0, stream>>>(
                feat, fb, row_ptr, col, nullptr, hb);
            gemm_mfma_kernel<true, true><<<gblocks, 256, 0, stream>>>(
                feat, fb, wb, b_self, hb, nullptr, out);
        } else if (ws_size >= NEED_LARGE) {
            fcvt_kernel<<<fblocks, 256, 0, stream>>>(feat, fb);
            aggregate_kernel<true, false><<<ablocks, 256, 0, stream>>>(
                feat, fb, row_ptr, col, out, nullptr);
            gemm_mfma_kernel<true, false><<<gblocks, 256, 0, stream>>>(
                feat, fb, wb, b_self, nullptr, out, out);
        } else {
            aggregate_kernel<false, false><<<ablocks, 256, 0, stream>>>(
                feat, nullptr, row_ptr, col, out, nullptr);
            gemm_mfma_kernel<false, false><<<gblocks, 256, 0, stream>>>(
                feat, nullptr, wb, b_self, nullptr, out, out);
        }
    } else {
        float* deg = (float*)d_ws;
        hipMemsetAsync(out, 0, (size_t)N_NODES * D * sizeof(float), stream);
        hipMemsetAsync(deg, 0, (size_t)N_NODES * sizeof(float), stream);
        scatter_kernel<<<4096, 256, 0, stream>>>(feat, src, dst, out, deg);
        fused_gemm_f32<<<(N_NODES + BM - 1) / BM, 256, 0, stream>>>(
            feat, w_neigh, w_self, b_self, deg, out);
    }
}

// Round 6
// 447.477 us; speedup vs baseline: 13.2803x; 1.2081x over previous
//
#include <hip/hip_runtime.h>
#include <cstddef>

#define N_NODES 100000
#define N_EDGES 1600000
#define D 256

typedef short  s16x8 __attribute__((ext_vector_type(8)));
typedef float  f32x4 __attribute__((ext_vector_type(4)));
typedef float  f32x8 __attribute__((ext_vector_type(8)));

__device__ __forceinline__ unsigned short f2bf(float f) {
    unsigned int u = __float_as_uint(f);
    unsigned int r = (u + 0x7fffu + ((u >> 16) & 1u)) >> 16;   // RNE
    return (unsigned short)r;
}
__device__ __forceinline__ float bf2f(unsigned short u) {
    return __uint_as_float(((unsigned int)u) << 16);
}

// ---------------------------------------------------------------------------
// Workspace layout:
//   ints:  [0,N) counts/cursor | [N,2N+1) row_ptr | [2N+16,+E) col | +128 part
//   bytes: WB_BYTE  weights bf16 (self 65536, neigh 65536 ushorts)
//          FB_BYTE  feat bf16 (N*256 ushorts)                  [LARGE & XL]
//          HB2_BYTE H bf16   (N*256 ushorts)                   [XL only]
// ---------------------------------------------------------------------------
#define WS_COUNTS 0
#define WS_ROWPTR (N_NODES)
#define WS_COL    (2 * N_NODES + 16)
#define WS_PART   (WS_COL + N_EDGES)
#define WB_BYTE   ((size_t)(WS_PART + 128) * 4)            // 7,200,576
#define FB_BYTE   (WB_BYTE + 2 * 65536 * 2)                // 7,462,720
#define FB_SZ     ((size_t)N_NODES * D * 2)                // 51,200,000
#define HB2_BYTE  (FB_BYTE + FB_SZ)
#define NEED_LARGE (FB_BYTE + FB_SZ)                       // 58.66 MB
#define NEED_XL    (HB2_BYTE + FB_SZ)                      // 109.9 MB
#define NEED_MID   (FB_BYTE)                               // 7.46 MB

// ---------------------------------------------------------------------------
__global__ __launch_bounds__(256) void hist_kernel(
    const int* __restrict__ dst, int* __restrict__ counts)
{
    const int i = blockIdx.x * 256 + threadIdx.x;
    if (i < N_EDGES) atomicAdd(&counts[dst[i]], 1);
}

// ---- 3-phase scan ----------------------------------------------------------
#define SCAN_NB ((N_NODES + 1023) / 1024)   // 98

__global__ __launch_bounds__(1024) void scan_block_kernel(
    const int* __restrict__ counts, int* __restrict__ row_ptr,
    int* __restrict__ partials)
{
    __shared__ int wsum[16];
    const int t = threadIdx.x, b = blockIdx.x, i = b * 1024 + t;
    const int lane = t & 63, w = t >> 6;
    int x = (i < N_NODES) ? counts[i] : 0;
#pragma unroll
    for (int off = 1; off < 64; off <<= 1) {
        int y = __shfl_up(x, off, 64);
        if (lane >= off) x += y;
    }
    if (lane == 63) wsum[w] = x;
    __syncthreads();
    if (w == 0) {
        int s = (lane < 16) ? wsum[lane] : 0;
#pragma unroll
        for (int off = 1; off < 16; off <<= 1) {
            int y = __shfl_up(s, off, 64);
            if (lane >= off) s += y;
        }
        if (lane < 16) wsum[lane] = s;
    }
    __syncthreads();
    const int incl = x + (w > 0 ? wsum[w - 1] : 0);
    if (i < N_NODES) row_ptr[i + 1] = incl;
    if (t == 1023) partials[b] = incl;
}

__global__ __launch_bounds__(128) void scan_partials_kernel(int* partials)
{
    __shared__ int s[128];
    const int t = threadIdx.x;
    s[t] = (t < SCAN_NB) ? partials[t] : 0;
    __syncthreads();
#pragma unroll
    for (int off = 1; off < 128; off <<= 1) {
        int y = (t >= off) ? s[t - off] : 0;
        __syncthreads();
        s[t] += y;
        __syncthreads();
    }
    if (t < SCAN_NB) partials[t] = s[t];
}

__global__ __launch_bounds__(1024) void scan_add_kernel(
    const int* __restrict__ partials, int* __restrict__ row_ptr)
{
    const int t = threadIdx.x, b = blockIdx.x, i = b * 1024 + t;
    if (i < N_NODES) {
        const int off = (b > 0) ? partials[b - 1] : 0;
        row_ptr[i + 1] += off;
    }
    if (b == 0 && t == 0) row_ptr[0] = 0;
}

__global__ __launch_bounds__(256) void fill_kernel(
    const int* __restrict__ src, const int* __restrict__ dst,
    const int* __restrict__ row_ptr, int* __restrict__ cursor,
    int* __restrict__ col)
{
    const int i = blockIdx.x * 256 + threadIdx.x;
    if (i < N_EDGES) {
        const int d = dst[i];
        const int pos = atomicAdd(&cursor[d], 1);
        col[row_ptr[d] + pos] = src[i];
    }
}

// ---- weight fp32 -> bf16 ---------------------------------------------------
__global__ __launch_bounds__(256) void wcvt_kernel(
    const float* __restrict__ w_self, const float* __restrict__ w_neigh,
    unsigned short* __restrict__ wb)
{
    const int i = blockIdx.x * 256 + threadIdx.x;      // 0..32767, 4 elems each
    const bool isself = (i < 16384);
    const float* srcp = isself ? w_self : w_neigh;
    const int j = (isself ? i : i - 16384) * 4;
    const float4 v = *(const float4*)(srcp + j);
    ushort4 o;
    o.x = f2bf(v.x); o.y = f2bf(v.y); o.z = f2bf(v.z); o.w = f2bf(v.w);
    ((ushort4*)wb)[i] = o;
}

// ---- feat fp32 -> bf16 (8 elems/thread) ------------------------------------
__global__ __launch_bounds__(256) void fcvt_kernel(
    const float* __restrict__ feat, unsigned short* __restrict__ fb)
{
    const int i = blockIdx.x * 256 + threadIdx.x;      // 8 elems each
    const f32x8 v = ((const f32x8*)feat)[i];
    ushort4 a, b;
    a.x = f2bf(v[0]); a.y = f2bf(v[1]); a.z = f2bf(v[2]); a.w = f2bf(v[3]);
    b.x = f2bf(v[4]); b.y = f2bf(v[5]); b.z = f2bf(v[6]); b.w = f2bf(v[7]);
    ((ushort4*)fb)[i * 2 + 0] = a;
    ((ushort4*)fb)[i * 2 + 1] = b;
}

// ---- pull-mode aggregation: one wave per node ------------------------------
template <bool INBF16, bool OUTBF16>
__global__ __launch_bounds__(256) void aggregate_kernel(
    const float* __restrict__ feat, const unsigned short* __restrict__ featb,
    const int* __restrict__ row_ptr, const int* __restrict__ col,
    float* __restrict__ outf, unsigned short* __restrict__ outb)
{
    const int node = (blockIdx.x * blockDim.x + threadIdx.x) >> 6;
    const int lane = threadIdx.x & 63;
    if (node >= N_NODES) return;
    const int beg = row_ptr[node], end = row_ptr[node + 1];

    float4 a0 = make_float4(0.f, 0.f, 0.f, 0.f);
    float4 a1 = make_float4(0.f, 0.f, 0.f, 0.f);
    float4 a2 = make_float4(0.f, 0.f, 0.f, 0.f);
    float4 a3 = make_float4(0.f, 0.f, 0.f, 0.f);

#define ACC(acc, s)                                                          \
    do {                                                                     \
        if (INBF16) {                                                        \
            const ushort4 u = ((const ushort4*)(featb + (size_t)(s) * D))[lane]; \
            acc.x += bf2f(u.x); acc.y += bf2f(u.y);                          \
            acc.z += bf2f(u.z); acc.w += bf2f(u.w);                          \
        } else {                                                             \
            const float4 v = ((const float4*)(feat + (size_t)(s) * D))[lane];\
            acc.x += v.x; acc.y += v.y; acc.z += v.z; acc.w += v.w;          \
        }                                                                    \
    } while (0)

    int j = beg;
    for (; j + 3 < end; j += 4) {
        const int s0 = col[j], s1 = col[j + 1], s2 = col[j + 2], s3 = col[j + 3];
        ACC(a0, s0); ACC(a1, s1); ACC(a2, s2); ACC(a3, s3);
    }
    for (; j < end; ++j) { const int s0 = col[j]; ACC(a0, s0); }
#undef ACC

    const float invd = 1.0f / fmaxf((float)(end - beg), 1.0f);
    float4 r;
    r.x = ((a0.x + a1.x) + (a2.x + a3.x)) * invd;
    r.y = ((a0.y + a1.y) + (a2.y + a3.y)) * invd;
    r.z = ((a0.z + a1.z) + (a2.z + a3.z)) * invd;
    r.w = ((a0.w + a1.w) + (a2.w + a3.w)) * invd;
    if (OUTBF16) {
        ushort4 o;
        o.x = f2bf(r.x); o.y = f2bf(r.y); o.z = f2bf(r.z); o.w = f2bf(r.w);
        ((ushort4*)(outb + (size_t)node * D))[lane] = o;
    } else {
        ((float4*)(outf + (size_t)node * D))[lane] = r;
    }
}

// ---------------------------------------------------------------------------
// MFMA GEMM, 64x64 tile per wave.  Block = 4 waves = 64 rows x 256 cols
// (wave w owns col slice w*64).  Per K=32 step: 4 A-loads + 4 B-loads feed
// 16 MFMAs (load:MFMA = 0.5 vs 1.06 in the 16x256 layout).  A rows shared
// by the 4 waves via L1; weights L2-resident.
// A frag: row=lane&15 (+m*16), k=(lane>>4)*8+i.  B from bf16 [N][K] row-major.
// C/D: col=lane&15, row=(lane>>4)*4+reg.
// In-place MID path (h32 == outp): K-loop reads all cols of the block's rows;
// __syncthreads() before the epilogue stores keeps it race-free.
// ---------------------------------------------------------------------------
template <bool ABF16, bool HBF16>
__global__ __launch_bounds__(256) void gemm_mfma64_kernel(
    const float* __restrict__ feat, const unsigned short* __restrict__ featb,
    const unsigned short* __restrict__ wb,     // self @0, neigh @+65536
    const float* __restrict__ b_self,
    const unsigned short* __restrict__ hb, const float* h32,
    float* outp)
{
    const int lane = threadIdx.x & 63;
    const int wslice = threadIdx.x >> 6;       // 0..3: col slice
    const int row0 = blockIdx.x * 64;
    const int c0 = wslice * 64;
    const int nl = lane & 15;
    const int kg = lane >> 4;

    f32x4 acc[4][4];
#pragma unroll
    for (int m = 0; m < 4; ++m)
#pragma unroll
        for (int n = 0; n < 4; ++n) acc[m][n] = (f32x4){0.f, 0.f, 0.f, 0.f};

    size_t aoff[4];
#pragma unroll
    for (int m = 0; m < 4; ++m) {
        int r = row0 + m * 16 + nl;
        if (r > N_NODES - 1) r = N_NODES - 1;   // clamp: stays in this block's rows
        aoff[m] = (size_t)r * D + kg * 8;
    }

#pragma unroll
    for (int half = 0; half < 2; ++half) {
        const unsigned short* wh = wb + half * 65536 + (size_t)(c0 + nl) * 256 + kg * 8;
#pragma unroll
        for (int kk = 0; kk < 8; ++kk) {
            const int kb = kk * 32;
            s16x8 afrag[4];
#pragma unroll
            for (int m = 0; m < 4; ++m) {
                if (half == 0) {
                    if (ABF16) {
                        afrag[m] = *(const s16x8*)(featb + aoff[m] + kb);
                    } else {
                        const f32x8 av = *(const f32x8*)(feat + aoff[m] + kb);
#pragma unroll
                        for (int i = 0; i < 8; ++i) afrag[m][i] = (short)f2bf(av[i]);
                    }
                } else if (HBF16) {
                    afrag[m] = *(const s16x8*)(hb + aoff[m] + kb);
                } else {
                    const f32x8 av = *(const f32x8*)(h32 + aoff[m] + kb);
#pragma unroll
                    for (int i = 0; i < 8; ++i) afrag[m][i] = (short)f2bf(av[i]);
                }
            }
            s16x8 bfrag[4];
#pragma unroll
            for (int n = 0; n < 4; ++n)
                bfrag[n] = *(const s16x8*)(wh + n * 16 * 256 + kb);
#pragma unroll
            for (int m = 0; m < 4; ++m)
#pragma unroll
                for (int n = 0; n < 4; ++n)
                    acc[m][n] = __builtin_amdgcn_mfma_f32_16x16x32_bf16(
                        afrag[m], bfrag[n], acc[m][n], 0, 0, 0);
        }
    }

    __syncthreads();   // in-place path: all A reads of out rows done before stores

#pragma unroll
    for (int n = 0; n < 4; ++n) {
        const float bias = b_self[c0 + n * 16 + nl];
#pragma unroll
        for (int m = 0; m < 4; ++m) {
            const int rbase = row0 + m * 16 + kg * 4;
#pragma unroll
            for (int r = 0; r < 4; ++r) {
                const int row = rbase + r;
                if (row < N_NODES)
                    outp[(size_t)row * D + c0 + n * 16 + nl] = acc[m][n][r] + bias;
            }
        }
    }
}

// ---------------------------------------------------------------------------
// Atomic fallback path (tiny ws)
// ---------------------------------------------------------------------------
__global__ __launch_bounds__(256) void scatter_kernel(
    const float* __restrict__ feat, const int* __restrict__ src,
    const int* __restrict__ dst, float* __restrict__ S, float* __restrict__ deg)
{
    const int gtid = blockIdx.x * blockDim.x + threadIdx.x;
    const int wave = gtid >> 6;
    const int lane = gtid & 63;
    const int nwaves = (gridDim.x * blockDim.x) >> 6;
    for (int e = wave; e < N_EDGES; e += nwaves) {
        const int s = src[e];
        const int d = dst[e];
        if (lane == 0) unsafeAtomicAdd(&deg[d], 1.0f);
        const float4 v = ((const float4*)(feat + (size_t)s * D))[lane];
        float* o = S + (size_t)d * D + lane * 4;
        unsafeAtomicAdd(o + 0, v.x);
        unsafeAtomicAdd(o + 1, v.y);
        unsafeAtomicAdd(o + 2, v.z);
        unsafeAtomicAdd(o + 3, v.w);
    }
}

#define BM 64
#define BK 16

__global__ __launch_bounds__(256) void fused_gemm_f32(
    const float* __restrict__ feat, const float* __restrict__ w_neigh,
    const float* __restrict__ w_self, const float* __restrict__ b_self,
    const float* __restrict__ deg, float* out)
{
    __shared__ float At[BK][BM + 4];
    __shared__ float Bt[BK][256];

    const int tid = threadIdx.x;
    const int i0 = blockIdx.x * BM;
    const int trow = tid >> 4;
    const int tcol = tid & 15;
    const int m_load = tid >> 2;
    const int kq = tid & 3;

    const int arow = i0 + m_load;
    const bool arow_ok = arow < N_NODES;
    float invd = 1.0f;
    if (arow_ok) invd = 1.0f / fmaxf(deg[arow], 1.0f);

    float acc[4][16];
#pragma unroll
    for (int r = 0; r < 4; ++r)
#pragma unroll
        for (int c = 0; c < 16; ++c) acc[r][c] = 0.0f;

    for (int kc = 0; kc < (2 * D) / BK; ++kc) {
        const int kb = kc * BK;
        const bool self_part = (kb < D);
        const int kbase = self_part ? kb : (kb - D);

        float4 va = make_float4(0.f, 0.f, 0.f, 0.f);
        if (arow_ok) {
            const float* ap = self_part ? feat : out;
            va = *(const float4*)(ap + (size_t)arow * D + kbase + kq * 4);
            if (!self_part) { va.x *= invd; va.y *= invd; va.z *= invd; va.w *= invd; }
        }
        const float* W = self_part ? w_self : w_neigh;
        const float4* wp = (const float4*)(W + (size_t)tid * D + kbase);
        const float4 w0 = wp[0], w1 = wp[1], w2 = wp[2], w3 = wp[3];

        __syncthreads();
        At[kq * 4 + 0][m_load] = va.x;
        At[kq * 4 + 1][m_load] = va.y;
        At[kq * 4 + 2][m_load] = va.z;
        At[kq * 4 + 3][m_load] = va.w;
        Bt[ 0][tid] = w0.x; Bt[ 1][tid] = w0.y; Bt[ 2][tid] = w0.z; Bt[ 3][tid] = w0.w;
        Bt[ 4][tid] = w1.x; Bt[ 5][tid] = w1.y; Bt[ 6][tid] = w1.z; Bt[ 7][tid] = w1.w;
        Bt[ 8][tid] = w2.x; Bt[ 9][tid] = w2.y; Bt[10][tid] = w2.z; Bt[11][tid] = w2.w;
        Bt[12][tid] = w3.x; Bt[13][tid] = w3.y; Bt[14][tid] = w3.z; Bt[15][tid] = w3.w;
        __syncthreads();

#pragma unroll
        for (int k = 0; k < BK; ++k) {
            const float4 a = *(const float4*)&At[k][trow * 4];
            float4 b[4];
#pragma unroll
            for (int g = 0; g < 4; ++g)
                b[g] = *(const float4*)&Bt[k][g * 64 + tcol * 4];
            const float av[4] = {a.x, a.y, a.z, a.w};
#pragma unroll
            for (int r = 0; r < 4; ++r)
#pragma unroll
                for (int g = 0; g < 4; ++g) {
                    acc[r][g * 4 + 0] = fmaf(av[r], b[g].x, acc[r][g * 4 + 0]);
                    acc[r][g * 4 + 1] = fmaf(av[r], b[g].y, acc[r][g * 4 + 1]);
                    acc[r][g * 4 + 2] = fmaf(av[r], b[g].z, acc[r][g * 4 + 2]);
                    acc[r][g * 4 + 3] = fmaf(av[r], b[g].w, acc[r][g * 4 + 3]);
                }
        }
    }

    float4 bias[4];
#pragma unroll
    for (int g = 0; g < 4; ++g)
        bias[g] = *(const float4*)&b_self[g * 64 + tcol * 4];

#pragma unroll
    for (int r = 0; r < 4; ++r) {
        const int row = i0 + trow * 4 + r;
        if (row < N_NODES) {
            float* op = out + (size_t)row * D;
#pragma unroll
            for (int g = 0; g < 4; ++g) {
                float4 v;
                v.x = acc[r][g * 4 + 0] + bias[g].x;
                v.y = acc[r][g * 4 + 1] + bias[g].y;
                v.z = acc[r][g * 4 + 2] + bias[g].z;
                v.w = acc[r][g * 4 + 3] + bias[g].w;
                *(float4*)(op + g * 64 + tcol * 4) = v;
            }
        }
    }
}

// ---------------------------------------------------------------------------
extern "C" void kernel_launch(void* const* d_in, const int* in_sizes, int n_in,
                              void* d_out, int out_size, void* d_ws, size_t ws_size,
                              hipStream_t stream) {
    const float* feat    = (const float*)d_in[0];
    const int*   src     = (const int*)d_in[1];
    const int*   dst     = (const int*)d_in[2];
    const float* w_neigh = (const float*)d_in[3];
    const float* w_self  = (const float*)d_in[4];
    const float* b_self  = (const float*)d_in[5];
    float* out = (float*)d_out;

    const int eblocks = (N_EDGES + 255) / 256;
    const int ablocks = (N_NODES * 64 + 255) / 256;        // 1 wave/node
    const int gblocks = (N_NODES + 63) / 64;               // 64 rows/block
    const int fblocks = (N_NODES * D / 8 + 255) / 256;     // fcvt

    if (ws_size >= NEED_MID) {
        int* wsI     = (int*)d_ws;
        int* counts  = wsI + WS_COUNTS;
        int* row_ptr = wsI + WS_ROWPTR;
        int* col     = wsI + WS_COL;
        int* part    = wsI + WS_PART;
        unsigned short* wb = (unsigned short*)((char*)d_ws + WB_BYTE);
        unsigned short* fb = (unsigned short*)((char*)d_ws + FB_BYTE);
        unsigned short* hb = (unsigned short*)((char*)d_ws + HB2_BYTE);

        hipMemsetAsync(counts, 0, N_NODES * sizeof(int), stream);
        hist_kernel<<<eblocks, 256, 0, stream>>>(dst, counts);
        scan_block_kernel<<<SCAN_NB, 1024, 0, stream>>>(counts, row_ptr, part);
        scan_partials_kernel<<<1, 128, 0, stream>>>(part);
        scan_add_kernel<<<SCAN_NB, 1024, 0, stream>>>(part, row_ptr);
        hipMemsetAsync(counts, 0, N_NODES * sizeof(int), stream);
        fill_kernel<<<eblocks, 256, 0, stream>>>(src, dst, row_ptr, counts, col);
        wcvt_kernel<<<128, 256, 0, stream>>>(w_self, w_neigh, wb);

        if (ws_size >= NEED_XL) {
            fcvt_kernel<<<fblocks, 256, 0, stream>>>(feat, fb);
            aggregate_kernel<true, true><<<ablocks, 256, 0, stream>>>(
                feat, fb, row_ptr, col, nullptr, hb);
            gemm_mfma64_kernel<true, true><<<gblocks, 256, 0, stream>>>(
                feat, fb, wb, b_self, hb, nullptr, out);
        } else if (ws_size >= NEED_LARGE) {
            fcvt_kernel<<<fblocks, 256, 0, stream>>>(feat, fb);
            aggregate_kernel<true, false><<<ablocks, 256, 0, stream>>>(
                feat, fb, row_ptr, col, out, nullptr);
            gemm_mfma64_kernel<true, false><<<gblocks, 256, 0, stream>>>(
                feat, fb, wb, b_self, nullptr, out, out);
        } else {
            aggregate_kernel<false, false><<<ablocks, 256, 0, stream>>>(
                feat, nullptr, row_ptr, col, out, nullptr);
            gemm_mfma64_kernel<false, false><<<gblocks, 256, 0, stream>>>(
                feat, nullptr, wb, b_self, nullptr, out, out);
        }
    } else {
        float* deg = (float*)d_ws;
        hipMemsetAsync(out, 0, (size_t)N_NODES * D * sizeof(float), stream);
        hipMemsetAsync(deg, 0, (size_t)N_NODES * sizeof(float), stream);
        scatter_kernel<<<4096, 256, 0, stream>>>(feat, src, dst, out, deg);
        fused_gemm_f32<<<(N_NODES + BM - 1) / BM, 256, 0, stream>>>(
            feat, w_neigh, w_self, b_self, deg, out);
    }
}

// Round 7
// 443.011 us; speedup vs baseline: 13.4142x; 1.0101x over previous
//
#include <hip/hip_runtime.h>
#include <cstddef>

#define N_NODES 100000
#define N_EDGES 1600000
#define D 256

typedef short          s16x8 __attribute__((ext_vector_type(8)));
typedef unsigned short u16x8 __attribute__((ext_vector_type(8)));
typedef float          f32x4 __attribute__((ext_vector_type(4)));
typedef float          f32x8 __attribute__((ext_vector_type(8)));

__device__ __forceinline__ unsigned short f2bf(float f) {
    unsigned int u = __float_as_uint(f);
    unsigned int r = (u + 0x7fffu + ((u >> 16) & 1u)) >> 16;   // RNE
    return (unsigned short)r;
}
__device__ __forceinline__ float bf2f(unsigned short u) {
    return __uint_as_float(((unsigned int)u) << 16);
}

// ---------------------------------------------------------------------------
// Workspace layout:
//   ints:  [0,N) counts/cursor | [N,2N+1) row_ptr | [2N+16,+E) col | +128 part
//   bytes: WB_BYTE  weights bf16 (self 65536, neigh 65536 ushorts)
//          FB_BYTE  feat bf16 (N*256 ushorts)                  [LARGE & XL]
//          HB2_BYTE H bf16   (N*256 ushorts)                   [XL only]
// ---------------------------------------------------------------------------
#define WS_COUNTS 0
#define WS_ROWPTR (N_NODES)
#define WS_COL    (2 * N_NODES + 16)
#define WS_PART   (WS_COL + N_EDGES)
#define WB_BYTE   ((size_t)(WS_PART + 128) * 4)            // 7,200,576
#define FB_BYTE   (WB_BYTE + 2 * 65536 * 2)                // 7,462,720
#define FB_SZ     ((size_t)N_NODES * D * 2)                // 51,200,000
#define HB2_BYTE  (FB_BYTE + FB_SZ)
#define NEED_LARGE (FB_BYTE + FB_SZ)                       // 58.66 MB
#define NEED_XL    (HB2_BYTE + FB_SZ)                      // 109.9 MB
#define NEED_MID   (FB_BYTE)                               // 7.46 MB

// ---------------------------------------------------------------------------
__global__ __launch_bounds__(256) void hist_kernel(
    const int* __restrict__ dst, int* __restrict__ counts)
{
    const int i = blockIdx.x * 256 + threadIdx.x;
    if (i < N_EDGES) atomicAdd(&counts[dst[i]], 1);
}

// ---- 3-phase scan ----------------------------------------------------------
#define SCAN_NB ((N_NODES + 1023) / 1024)   // 98

__global__ __launch_bounds__(1024) void scan_block_kernel(
    const int* __restrict__ counts, int* __restrict__ row_ptr,
    int* __restrict__ partials)
{
    __shared__ int wsum[16];
    const int t = threadIdx.x, b = blockIdx.x, i = b * 1024 + t;
    const int lane = t & 63, w = t >> 6;
    int x = (i < N_NODES) ? counts[i] : 0;
#pragma unroll
    for (int off = 1; off < 64; off <<= 1) {
        int y = __shfl_up(x, off, 64);
        if (lane >= off) x += y;
    }
    if (lane == 63) wsum[w] = x;
    __syncthreads();
    if (w == 0) {
        int s = (lane < 16) ? wsum[lane] : 0;
#pragma unroll
        for (int off = 1; off < 16; off <<= 1) {
            int y = __shfl_up(s, off, 64);
            if (lane >= off) s += y;
        }
        if (lane < 16) wsum[lane] = s;
    }
    __syncthreads();
    const int incl = x + (w > 0 ? wsum[w - 1] : 0);
    if (i < N_NODES) row_ptr[i + 1] = incl;
    if (t == 1023) partials[b] = incl;
}

__global__ __launch_bounds__(128) void scan_partials_kernel(int* partials)
{
    __shared__ int s[128];
    const int t = threadIdx.x;
    s[t] = (t < SCAN_NB) ? partials[t] : 0;
    __syncthreads();
#pragma unroll
    for (int off = 1; off < 128; off <<= 1) {
        int y = (t >= off) ? s[t - off] : 0;
        __syncthreads();
        s[t] += y;
        __syncthreads();
    }
    if (t < SCAN_NB) partials[t] = s[t];
}

__global__ __launch_bounds__(1024) void scan_add_kernel(
    const int* __restrict__ partials, int* __restrict__ row_ptr)
{
    const int t = threadIdx.x, b = blockIdx.x, i = b * 1024 + t;
    if (i < N_NODES) {
        const int off = (b > 0) ? partials[b - 1] : 0;
        row_ptr[i + 1] += off;
    }
    if (b == 0 && t == 0) row_ptr[0] = 0;
}

__global__ __launch_bounds__(256) void fill_kernel(
    const int* __restrict__ src, const int* __restrict__ dst,
    const int* __restrict__ row_ptr, int* __restrict__ cursor,
    int* __restrict__ col)
{
    const int i = blockIdx.x * 256 + threadIdx.x;
    if (i < N_EDGES) {
        const int d = dst[i];
        const int pos = atomicAdd(&cursor[d], 1);
        col[row_ptr[d] + pos] = src[i];
    }
}

// ---- fused feat+weights fp32 -> bf16 --------------------------------------
#define FBLOCKS (N_NODES * D / 8 / 256)    // 12500 (exact)

__global__ __launch_bounds__(256) void cvt_kernel(
    const float* __restrict__ feat, const float* __restrict__ w_self,
    const float* __restrict__ w_neigh, unsigned short* __restrict__ fb,
    unsigned short* __restrict__ wb)
{
    const int b = blockIdx.x;
    if (b < FBLOCKS) {
        const int i = b * 256 + threadIdx.x;           // 8 elems each
        const f32x8 v = ((const f32x8*)feat)[i];
        ushort4 a, c;
        a.x = f2bf(v[0]); a.y = f2bf(v[1]); a.z = f2bf(v[2]); a.w = f2bf(v[3]);
        c.x = f2bf(v[4]); c.y = f2bf(v[5]); c.z = f2bf(v[6]); c.w = f2bf(v[7]);
        ((ushort4*)fb)[i * 2 + 0] = a;
        ((ushort4*)fb)[i * 2 + 1] = c;
    } else {
        const int i = (b - FBLOCKS) * 256 + threadIdx.x;   // 0..32767, 4 each
        const bool isself = (i < 16384);
        const float* srcp = isself ? w_self : w_neigh;
        const int j = (isself ? i : i - 16384) * 4;
        const float4 v = *(const float4*)(srcp + j);
        ushort4 o;
        o.x = f2bf(v.x); o.y = f2bf(v.y); o.z = f2bf(v.z); o.w = f2bf(v.w);
        ((ushort4*)wb)[i] = o;
    }
}

// ---- pull aggregation v2: one wave per node, 2 rows/load, 8 edges in flight
// Half-wave h (32 lanes) covers a full 512B bf16 row with ushort8 (16B/lane);
// half 0 takes edges beg, beg+2, ...; half 1 takes beg+1, beg+3, ...
// 4 streams -> 8 edges outstanding.  Cross-half combine via shfl_xor(32).
template <bool OUTBF16>
__global__ __launch_bounds__(256) void aggregate2_kernel(
    const unsigned short* __restrict__ featb,
    const int* __restrict__ row_ptr, const int* __restrict__ col,
    float* __restrict__ outf, unsigned short* __restrict__ outb)
{
    const int node = (blockIdx.x * blockDim.x + threadIdx.x) >> 6;
    const int lane = threadIdx.x & 63;
    if (node >= N_NODES) return;
    const int beg = row_ptr[node], end = row_ptr[node + 1];
    const int half = lane >> 5;        // 0 or 1
    const int chunk = lane & 31;       // elems chunk*8 .. chunk*8+7

    float a0[8] = {0,0,0,0,0,0,0,0};
    float a1[8] = {0,0,0,0,0,0,0,0};
    float a2[8] = {0,0,0,0,0,0,0,0};
    float a3[8] = {0,0,0,0,0,0,0,0};

    const unsigned short* fbp = featb + chunk * 8;

    int j = beg + half;
    for (; j + 6 < end; j += 8) {
        const int s0 = col[j], s1 = col[j + 2], s2 = col[j + 4], s3 = col[j + 6];
        const u16x8 u0 = *(const u16x8*)(fbp + (size_t)s0 * D);
        const u16x8 u1 = *(const u16x8*)(fbp + (size_t)s1 * D);
        const u16x8 u2 = *(const u16x8*)(fbp + (size_t)s2 * D);
        const u16x8 u3 = *(const u16x8*)(fbp + (size_t)s3 * D);
#pragma unroll
        for (int i = 0; i < 8; ++i) a0[i] += bf2f(u0[i]);
#pragma unroll
        for (int i = 0; i < 8; ++i) a1[i] += bf2f(u1[i]);
#pragma unroll
        for (int i = 0; i < 8; ++i) a2[i] += bf2f(u2[i]);
#pragma unroll
        for (int i = 0; i < 8; ++i) a3[i] += bf2f(u3[i]);
    }
    for (; j < end; j += 2) {
        const int s0 = col[j];
        const u16x8 u0 = *(const u16x8*)(fbp + (size_t)s0 * D);
#pragma unroll
        for (int i = 0; i < 8; ++i) a0[i] += bf2f(u0[i]);
    }

    const float invd = 1.0f / fmaxf((float)(end - beg), 1.0f);
    float t[8];
#pragma unroll
    for (int i = 0; i < 8; ++i) {
        float v = (a0[i] + a1[i]) + (a2[i] + a3[i]);
        v += __shfl_xor(v, 32, 64);            // combine the two halves
        t[i] = v * invd;
    }

    if (OUTBF16) {
        if (half == 0) {
            u16x8 o;
#pragma unroll
            for (int i = 0; i < 8; ++i) o[i] = f2bf(t[i]);
            *(u16x8*)(outb + (size_t)node * D + chunk * 8) = o;
        }
    } else {
        // half 0 writes elems [chunk*8, +4), half 1 writes [chunk*8+4, +4)
        float4 o;
        o.x = t[half * 4 + 0]; o.y = t[half * 4 + 1];
        o.z = t[half * 4 + 2]; o.w = t[half * 4 + 3];
        *(float4*)(outf + (size_t)node * D + chunk * 8 + half * 4) = o;
    }
}

// ---- legacy aggregation (fp32 gather, MID tier) ----------------------------
__global__ __launch_bounds__(256) void aggregate_f32_kernel(
    const float* __restrict__ feat, const int* __restrict__ row_ptr,
    const int* __restrict__ col, float* __restrict__ outf)
{
    const int node = (blockIdx.x * blockDim.x + threadIdx.x) >> 6;
    const int lane = threadIdx.x & 63;
    if (node >= N_NODES) return;
    const int beg = row_ptr[node], end = row_ptr[node + 1];

    float4 a0 = make_float4(0.f, 0.f, 0.f, 0.f);
    float4 a1 = make_float4(0.f, 0.f, 0.f, 0.f);
    float4 a2 = make_float4(0.f, 0.f, 0.f, 0.f);
    float4 a3 = make_float4(0.f, 0.f, 0.f, 0.f);

#define ACC(acc, s)                                                          \
    do {                                                                     \
        const float4 v = ((const float4*)(feat + (size_t)(s) * D))[lane];    \
        acc.x += v.x; acc.y += v.y; acc.z += v.z; acc.w += v.w;              \
    } while (0)

    int j = beg;
    for (; j + 3 < end; j += 4) {
        const int s0 = col[j], s1 = col[j + 1], s2 = col[j + 2], s3 = col[j + 3];
        ACC(a0, s0); ACC(a1, s1); ACC(a2, s2); ACC(a3, s3);
    }
    for (; j < end; ++j) { const int s0 = col[j]; ACC(a0, s0); }
#undef ACC

    const float invd = 1.0f / fmaxf((float)(end - beg), 1.0f);
    float4 r;
    r.x = ((a0.x + a1.x) + (a2.x + a3.x)) * invd;
    r.y = ((a0.y + a1.y) + (a2.y + a3.y)) * invd;
    r.z = ((a0.z + a1.z) + (a2.z + a3.z)) * invd;
    r.w = ((a0.w + a1.w) + (a2.w + a3.w)) * invd;
    ((float4*)(outf + (size_t)node * D))[lane] = r;
}

// ---------------------------------------------------------------------------
// MFMA GEMM, 64x64 tile per wave.  Block = 4 waves = 64 rows x 256 cols.
// Per K=32 step: 4 A-loads + 4 B-loads feed 16 MFMAs.
// ---------------------------------------------------------------------------
template <bool ABF16, bool HBF16>
__global__ __launch_bounds__(256) void gemm_mfma64_kernel(
    const float* __restrict__ feat, const unsigned short* __restrict__ featb,
    const unsigned short* __restrict__ wb,     // self @0, neigh @+65536
    const float* __restrict__ b_self,
    const unsigned short* __restrict__ hb, const float* h32,
    float* outp)
{
    const int lane = threadIdx.x & 63;
    const int wslice = threadIdx.x >> 6;       // 0..3: col slice
    const int row0 = blockIdx.x * 64;
    const int c0 = wslice * 64;
    const int nl = lane & 15;
    const int kg = lane >> 4;

    f32x4 acc[4][4];
#pragma unroll
    for (int m = 0; m < 4; ++m)
#pragma unroll
        for (int n = 0; n < 4; ++n) acc[m][n] = (f32x4){0.f, 0.f, 0.f, 0.f};

    size_t aoff[4];
#pragma unroll
    for (int m = 0; m < 4; ++m) {
        int r = row0 + m * 16 + nl;
        if (r > N_NODES - 1) r = N_NODES - 1;   // clamp within block's rows
        aoff[m] = (size_t)r * D + kg * 8;
    }

#pragma unroll
    for (int half = 0; half < 2; ++half) {
        const unsigned short* wh = wb + half * 65536 + (size_t)(c0 + nl) * 256 + kg * 8;
#pragma unroll
        for (int kk = 0; kk < 8; ++kk) {
            const int kb = kk * 32;
            s16x8 afrag[4];
#pragma unroll
            for (int m = 0; m < 4; ++m) {
                if (half == 0) {
                    if (ABF16) {
                        afrag[m] = *(const s16x8*)(featb + aoff[m] + kb);
                    } else {
                        const f32x8 av = *(const f32x8*)(feat + aoff[m] + kb);
#pragma unroll
                        for (int i = 0; i < 8; ++i) afrag[m][i] = (short)f2bf(av[i]);
                    }
                } else if (HBF16) {
                    afrag[m] = *(const s16x8*)(hb + aoff[m] + kb);
                } else {
                    const f32x8 av = *(const f32x8*)(h32 + aoff[m] + kb);
#pragma unroll
                    for (int i = 0; i < 8; ++i) afrag[m][i] = (short)f2bf(av[i]);
                }
            }
            s16x8 bfrag[4];
#pragma unroll
            for (int n = 0; n < 4; ++n)
                bfrag[n] = *(const s16x8*)(wh + n * 16 * 256 + kb);
#pragma unroll
            for (int m = 0; m < 4; ++m)
#pragma unroll
                for (int n = 0; n < 4; ++n)
                    acc[m][n] = __builtin_amdgcn_mfma_f32_16x16x32_bf16(
                        afrag[m], bfrag[n], acc[m][n], 0, 0, 0);
        }
    }

    __syncthreads();   // in-place path: A reads of out rows done before stores

#pragma unroll
    for (int n = 0; n < 4; ++n) {
        const float bias = b_self[c0 + n * 16 + nl];
#pragma unroll
        for (int m = 0; m < 4; ++m) {
            const int rbase = row0 + m * 16 + kg * 4;
#pragma unroll
            for (int r = 0; r < 4; ++r) {
                const int row = rbase + r;
                if (row < N_NODES)
                    outp[(size_t)row * D + c0 + n * 16 + nl] = acc[m][n][r] + bias;
            }
        }
    }
}

// ---------------------------------------------------------------------------
// Atomic fallback path (tiny ws)
// ---------------------------------------------------------------------------
__global__ __launch_bounds__(256) void scatter_kernel(
    const float* __restrict__ feat, const int* __restrict__ src,
    const int* __restrict__ dst, float* __restrict__ S, float* __restrict__ deg)
{
    const int gtid = blockIdx.x * blockDim.x + threadIdx.x;
    const int wave = gtid >> 6;
    const int lane = gtid & 63;
    const int nwaves = (gridDim.x * blockDim.x) >> 6;
    for (int e = wave; e < N_EDGES; e += nwaves) {
        const int s = src[e];
        const int d = dst[e];
        if (lane == 0) unsafeAtomicAdd(&deg[d], 1.0f);
        const float4 v = ((const float4*)(feat + (size_t)s * D))[lane];
        float* o = S + (size_t)d * D + lane * 4;
        unsafeAtomicAdd(o + 0, v.x);
        unsafeAtomicAdd(o + 1, v.y);
        unsafeAtomicAdd(o + 2, v.z);
        unsafeAtomicAdd(o + 3, v.w);
    }
}

#define BM 64
#define BK 16

__global__ __launch_bounds__(256) void fused_gemm_f32(
    const float* __restrict__ feat, const float* __restrict__ w_neigh,
    const float* __restrict__ w_self, const float* __restrict__ b_self,
    const float* __restrict__ deg, float* out)
{
    __shared__ float At[BK][BM + 4];
    __shared__ float Bt[BK][256];

    const int tid = threadIdx.x;
    const int i0 = blockIdx.x * BM;
    const int trow = tid >> 4;
    const int tcol = tid & 15;
    const int m_load = tid >> 2;
    const int kq = tid & 3;

    const int arow = i0 + m_load;
    const bool arow_ok = arow < N_NODES;
    float invd = 1.0f;
    if (arow_ok) invd = 1.0f / fmaxf(deg[arow], 1.0f);

    float acc[4][16];
#pragma unroll
    for (int r = 0; r < 4; ++r)
#pragma unroll
        for (int c = 0; c < 16; ++c) acc[r][c] = 0.0f;

    for (int kc = 0; kc < (2 * D) / BK; ++kc) {
        const int kb = kc * BK;
        const bool self_part = (kb < D);
        const int kbase = self_part ? kb : (kb - D);

        float4 va = make_float4(0.f, 0.f, 0.f, 0.f);
        if (arow_ok) {
            const float* ap = self_part ? feat : out;
            va = *(const float4*)(ap + (size_t)arow * D + kbase + kq * 4);
            if (!self_part) { va.x *= invd; va.y *= invd; va.z *= invd; va.w *= invd; }
        }
        const float* W = self_part ? w_self : w_neigh;
        const float4* wp = (const float4*)(W + (size_t)tid * D + kbase);
        const float4 w0 = wp[0], w1 = wp[1], w2 = wp[2], w3 = wp[3];

        __syncthreads();
        At[kq * 4 + 0][m_load] = va.x;
        At[kq * 4 + 1][m_load] = va.y;
        At[kq * 4 + 2][m_load] = va.z;
        At[kq * 4 + 3][m_load] = va.w;
        Bt[ 0][tid] = w0.x; Bt[ 1][tid] = w0.y; Bt[ 2][tid] = w0.z; Bt[ 3][tid] = w0.w;
        Bt[ 4][tid] = w1.x; Bt[ 5][tid] = w1.y; Bt[ 6][tid] = w1.z; Bt[ 7][tid] = w1.w;
        Bt[ 8][tid] = w2.x; Bt[ 9][tid] = w2.y; Bt[10][tid] = w2.z; Bt[11][tid] = w2.w;
        Bt[12][tid] = w3.x; Bt[13][tid] = w3.y; Bt[14][tid] = w3.z; Bt[15][tid] = w3.w;
        __syncthreads();

#pragma unroll
        for (int k = 0; k < BK; ++k) {
            const float4 a = *(const float4*)&At[k][trow * 4];
            float4 b[4];
#pragma unroll
            for (int g = 0; g < 4; ++g)
                b[g] = *(const float4*)&Bt[k][g * 64 + tcol * 4];
            const float av[4] = {a.x, a.y, a.z, a.w};
#pragma unroll
            for (int r = 0; r < 4; ++r)
#pragma unroll
                for (int g = 0; g < 4; ++g) {
                    acc[r][g * 4 + 0] = fmaf(av[r], b[g].x, acc[r][g * 4 + 0]);
                    acc[r][g * 4 + 1] = fmaf(av[r], b[g].y, acc[r][g * 4 + 1]);
                    acc[r][g * 4 + 2] = fmaf(av[r], b[g].z, acc[r][g * 4 + 2]);
                    acc[r][g * 4 + 3] = fmaf(av[r], b[g].w, acc[r][g * 4 + 3]);
                }
        }
    }

    float4 bias[4];
#pragma unroll
    for (int g = 0; g < 4; ++g)
        bias[g] = *(const float4*)&b_self[g * 64 + tcol * 4];

#pragma unroll
    for (int r = 0; r < 4; ++r) {
        const int row = i0 + trow * 4 + r;
        if (row < N_NODES) {
            float* op = out + (size_t)row * D;
#pragma unroll
            for (int g = 0; g < 4; ++g) {
                float4 v;
                v.x = acc[r][g * 4 + 0] + bias[g].x;
                v.y = acc[r][g * 4 + 1] + bias[g].y;
                v.z = acc[r][g * 4 + 2] + bias[g].z;
                v.w = acc[r][g * 4 + 3] + bias[g].w;
                *(float4*)(op + g * 64 + tcol * 4) = v;
            }
        }
    }
}

// ---------------------------------------------------------------------------
extern "C" void kernel_launch(void* const* d_in, const int* in_sizes, int n_in,
                              void* d_out, int out_size, void* d_ws, size_t ws_size,
                              hipStream_t stream) {
    const float* feat    = (const float*)d_in[0];
    const int*   src     = (const int*)d_in[1];
    const int*   dst     = (const int*)d_in[2];
    const float* w_neigh = (const float*)d_in[3];
    const float* w_self  = (const float*)d_in[4];
    const float* b_self  = (const float*)d_in[5];
    float* out = (float*)d_out;

    const int eblocks = (N_EDGES + 255) / 256;
    const int ablocks = (N_NODES * 64 + 255) / 256;        // 1 wave/node
    const int gblocks = (N_NODES + 63) / 64;               // 64 rows/block

    if (ws_size >= NEED_MID) {
        int* wsI     = (int*)d_ws;
        int* counts  = wsI + WS_COUNTS;
        int* row_ptr = wsI + WS_ROWPTR;
        int* col     = wsI + WS_COL;
        int* part    = wsI + WS_PART;
        unsigned short* wb = (unsigned short*)((char*)d_ws + WB_BYTE);
        unsigned short* fb = (unsigned short*)((char*)d_ws + FB_BYTE);
        unsigned short* hb = (unsigned short*)((char*)d_ws + HB2_BYTE);

        hipMemsetAsync(counts, 0, N_NODES * sizeof(int), stream);
        hist_kernel<<<eblocks, 256, 0, stream>>>(dst, counts);
        scan_block_kernel<<<SCAN_NB, 1024, 0, stream>>>(counts, row_ptr, part);
        scan_partials_kernel<<<1, 128, 0, stream>>>(part);
        scan_add_kernel<<<SCAN_NB, 1024, 0, stream>>>(part, row_ptr);
        hipMemsetAsync(counts, 0, N_NODES * sizeof(int), stream);
        fill_kernel<<<eblocks, 256, 0, stream>>>(src, dst, row_ptr, counts, col);

        if (ws_size >= NEED_XL) {
            cvt_kernel<<<FBLOCKS + 128, 256, 0, stream>>>(feat, w_self, w_neigh, fb, wb);
            aggregate2_kernel<true><<<ablocks, 256, 0, stream>>>(
                fb, row_ptr, col, nullptr, hb);
            gemm_mfma64_kernel<true, true><<<gblocks, 256, 0, stream>>>(
                feat, fb, wb, b_self, hb, nullptr, out);
        } else if (ws_size >= NEED_LARGE) {
            cvt_kernel<<<FBLOCKS + 128, 256, 0, stream>>>(feat, w_self, w_neigh, fb, wb);
            aggregate2_kernel<false><<<ablocks, 256, 0, stream>>>(
                fb, row_ptr, col, out, nullptr);
            gemm_mfma64_kernel<true, false><<<gblocks, 256, 0, stream>>>(
                feat, fb, wb, b_self, nullptr, out, out);
        } else {
            cvt_kernel<<<FBLOCKS + 128, 256, 0, stream>>>(feat, w_self, w_neigh, fb, wb);
            aggregate_f32_kernel<<<ablocks, 256, 0, stream>>>(
                feat, row_ptr, col, out);
            gemm_mfma64_kernel<false, false><<<gblocks, 256, 0, stream>>>(
                feat, nullptr, wb, b_self, nullptr, out, out);
        }
    } else {
        float* deg = (float*)d_ws;
        hipMemsetAsync(out, 0, (size_t)N_NODES * D * sizeof(float), stream);
        hipMemsetAsync(deg, 0, (size_t)N_NODES * sizeof(float), stream);
        scatter_kernel<<<4096, 256, 0, stream>>>(feat, src, dst, out, deg);
        fused_gemm_f32<<<(N_NODES + BM - 1) / BM, 256, 0, stream>>>(
            feat, w_neigh, w_self, b_self, deg, out);
    }
}

// Round 8
// 437.665 us; speedup vs baseline: 13.5780x; 1.0122x over previous
//
#include <hip/hip_runtime.h>
#include <cstddef>

#define N_NODES 100000
#define N_EDGES 1600000
#define D 256

typedef short          s16x8 __attribute__((ext_vector_type(8)));
typedef unsigned short u16x8 __attribute__((ext_vector_type(8)));
typedef float          f32x4 __attribute__((ext_vector_type(4)));
typedef float          f32x8 __attribute__((ext_vector_type(8)));

__device__ __forceinline__ unsigned short f2bf(float f) {
    unsigned int u = __float_as_uint(f);
    unsigned int r = (u + 0x7fffu + ((u >> 16) & 1u)) >> 16;   // RNE
    return (unsigned short)r;
}
__device__ __forceinline__ float bf2f(unsigned short u) {
    return __uint_as_float(((unsigned int)u) << 16);
}

// ---------------------------------------------------------------------------
// Workspace layout:
//   ints:  [0,N) counts/cursor | [N,2N+1) row_ptr | [2N+16,+E) col | +128 part
//   bytes: WB_BYTE  weights bf16 (self 65536, neigh 65536 ushorts)
//          FB_BYTE  feat bf16 (N*256 ushorts)                  [FULL tier]
// ---------------------------------------------------------------------------
#define WS_COUNTS 0
#define WS_ROWPTR (N_NODES)
#define WS_COL    (2 * N_NODES + 16)
#define WS_PART   (WS_COL + N_EDGES)
#define WB_BYTE   ((size_t)(WS_PART + 128) * 4)            // 7,200,576
#define FB_BYTE   (WB_BYTE + 2 * 65536 * 2)                // 7,462,720
#define FB_SZ     ((size_t)N_NODES * D * 2)                // 51,200,000
#define NEED_FULL (FB_BYTE + FB_SZ)                        // 58.66 MB
#define NEED_MID  (FB_BYTE)                                // 7.46 MB

// ---------------------------------------------------------------------------
__global__ __launch_bounds__(256) void hist_kernel(
    const int* __restrict__ dst, int* __restrict__ counts)
{
    const int i = blockIdx.x * 256 + threadIdx.x;
    if (i < N_EDGES) atomicAdd(&counts[dst[i]], 1);
}

// ---- 3-phase scan ----------------------------------------------------------
#define SCAN_NB ((N_NODES + 1023) / 1024)   // 98

__global__ __launch_bounds__(1024) void scan_block_kernel(
    const int* __restrict__ counts, int* __restrict__ row_ptr,
    int* __restrict__ partials)
{
    __shared__ int wsum[16];
    const int t = threadIdx.x, b = blockIdx.x, i = b * 1024 + t;
    const int lane = t & 63, w = t >> 6;
    int x = (i < N_NODES) ? counts[i] : 0;
#pragma unroll
    for (int off = 1; off < 64; off <<= 1) {
        int y = __shfl_up(x, off, 64);
        if (lane >= off) x += y;
    }
    if (lane == 63) wsum[w] = x;
    __syncthreads();
    if (w == 0) {
        int s = (lane < 16) ? wsum[lane] : 0;
#pragma unroll
        for (int off = 1; off < 16; off <<= 1) {
            int y = __shfl_up(s, off, 64);
            if (lane >= off) s += y;
        }
        if (lane < 16) wsum[lane] = s;
    }
    __syncthreads();
    const int incl = x + (w > 0 ? wsum[w - 1] : 0);
    if (i < N_NODES) row_ptr[i + 1] = incl;
    if (t == 1023) partials[b] = incl;
}

__global__ __launch_bounds__(128) void scan_partials_kernel(int* partials)
{
    __shared__ int s[128];
    const int t = threadIdx.x;
    s[t] = (t < SCAN_NB) ? partials[t] : 0;
    __syncthreads();
#pragma unroll
    for (int off = 1; off < 128; off <<= 1) {
        int y = (t >= off) ? s[t - off] : 0;
        __syncthreads();
        s[t] += y;
        __syncthreads();
    }
    if (t < SCAN_NB) partials[t] = s[t];
}

__global__ __launch_bounds__(1024) void scan_add_kernel(
    const int* __restrict__ partials, int* __restrict__ row_ptr)
{
    const int t = threadIdx.x, b = blockIdx.x, i = b * 1024 + t;
    if (i < N_NODES) {
        const int off = (b > 0) ? partials[b - 1] : 0;
        row_ptr[i + 1] += off;
    }
    if (b == 0 && t == 0) row_ptr[0] = 0;
}

__global__ __launch_bounds__(256) void fill_kernel(
    const int* __restrict__ src, const int* __restrict__ dst,
    const int* __restrict__ row_ptr, int* __restrict__ cursor,
    int* __restrict__ col)
{
    const int i = blockIdx.x * 256 + threadIdx.x;
    if (i < N_EDGES) {
        const int d = dst[i];
        const int pos = atomicAdd(&cursor[d], 1);
        col[row_ptr[d] + pos] = src[i];
    }
}

// ---- fused feat+weights fp32 -> bf16 --------------------------------------
#define FBLOCKS (N_NODES * D / 8 / 256)    // 12500 (exact)

__global__ __launch_bounds__(256) void cvt_kernel(
    const float* __restrict__ feat, const float* __restrict__ w_self,
    const float* __restrict__ w_neigh, unsigned short* __restrict__ fb,
    unsigned short* __restrict__ wb)
{
    const int b = blockIdx.x;
    if (b < FBLOCKS) {
        const int i = b * 256 + threadIdx.x;           // 8 elems each
        const f32x8 v = ((const f32x8*)feat)[i];
        ushort4 a, c;
        a.x = f2bf(v[0]); a.y = f2bf(v[1]); a.z = f2bf(v[2]); a.w = f2bf(v[3]);
        c.x = f2bf(v[4]); c.y = f2bf(v[5]); c.z = f2bf(v[6]); c.w = f2bf(v[7]);
        ((ushort4*)fb)[i * 2 + 0] = a;
        ((ushort4*)fb)[i * 2 + 1] = c;
    } else {
        const int i = (b - FBLOCKS) * 256 + threadIdx.x;   // 0..32767, 4 each
        const bool isself = (i < 16384);
        const float* srcp = isself ? w_self : w_neigh;
        const int j = (isself ? i : i - 16384) * 4;
        const float4 v = *(const float4*)(srcp + j);
        ushort4 o;
        o.x = f2bf(v.x); o.y = f2bf(v.y); o.z = f2bf(v.z); o.w = f2bf(v.w);
        ((ushort4*)wb)[i] = o;
    }
}

// ---- weights-only cvt (MID tier) ------------------------------------------
__global__ __launch_bounds__(256) void wcvt_kernel(
    const float* __restrict__ w_self, const float* __restrict__ w_neigh,
    unsigned short* __restrict__ wb)
{
    const int i = blockIdx.x * 256 + threadIdx.x;      // 0..32767, 4 each
    const bool isself = (i < 16384);
    const float* srcp = isself ? w_self : w_neigh;
    const int j = (isself ? i : i - 16384) * 4;
    const float4 v = *(const float4*)(srcp + j);
    ushort4 o;
    o.x = f2bf(v.x); o.y = f2bf(v.y); o.z = f2bf(v.z); o.w = f2bf(v.w);
    ((ushort4*)wb)[i] = o;
}

// ---------------------------------------------------------------------------
// FUSED aggregate + GEMM.
// Block = 4 waves, owns 64 rows x all 256 cols.
// Phase 1: each wave gathers 16 nodes' neighbor means (bf16 gather via CSR,
//   half-wave = one 512B row at 16B/lane, 4 edges in flight) into LDS Hs.
//   Hs row stride 264 ushorts (+16B pad) -> uniform bank coverage on b128.
// Phase 2: 64x64 MFMA tile per wave; A-self from fb (global), A-neigh from
//   Hs (LDS), B from bf16 weights (L2-resident).  out = A_s@Ws^T+A_n@Wn^T+b.
// Gather of block n+1 overlaps MFMA of block n (4 blocks/CU via lbounds).
// ---------------------------------------------------------------------------
#define HS_STRIDE 264

__global__ __launch_bounds__(256, 4) void fused_agg_gemm_kernel(
    const unsigned short* __restrict__ fb,
    const unsigned short* __restrict__ wb,     // self @0, neigh @+65536
    const float* __restrict__ b_self,
    const int* __restrict__ row_ptr, const int* __restrict__ col,
    float* __restrict__ outp)
{
    __shared__ unsigned short Hs[64][HS_STRIDE];   // 33,792 B

    const int lane = threadIdx.x & 63;
    const int wid  = threadIdx.x >> 6;         // 0..3
    const int row0 = blockIdx.x * 64;

    // ---------------- phase 1: gather -> LDS ----------------
    {
        const int half  = lane >> 5;           // 0/1: which edge parity
        const int chunk = lane & 31;           // 16B chunk of the row
        const unsigned short* fbp = fb + chunk * 8;

        for (int t = 0; t < 16; ++t) {
            const int local = (wid << 4) + t;  // 0..63
            const int node = row0 + local;
            int beg = 0, end = 0;
            if (node < N_NODES) { beg = row_ptr[node]; end = row_ptr[node + 1]; }

            float a0[8] = {0,0,0,0,0,0,0,0};
            float a1[8] = {0,0,0,0,0,0,0,0};
            float a2[8] = {0,0,0,0,0,0,0,0};
            float a3[8] = {0,0,0,0,0,0,0,0};

            int j = beg + half;
            for (; j + 6 < end; j += 8) {
                const int s0 = col[j],     s1 = col[j + 2];
                const int s2 = col[j + 4], s3 = col[j + 6];
                const u16x8 u0 = *(const u16x8*)(fbp + (size_t)s0 * D);
                const u16x8 u1 = *(const u16x8*)(fbp + (size_t)s1 * D);
                const u16x8 u2 = *(const u16x8*)(fbp + (size_t)s2 * D);
                const u16x8 u3 = *(const u16x8*)(fbp + (size_t)s3 * D);
#pragma unroll
                for (int i = 0; i < 8; ++i) a0[i] += bf2f(u0[i]);
#pragma unroll
                for (int i = 0; i < 8; ++i) a1[i] += bf2f(u1[i]);
#pragma unroll
                for (int i = 0; i < 8; ++i) a2[i] += bf2f(u2[i]);
#pragma unroll
                for (int i = 0; i < 8; ++i) a3[i] += bf2f(u3[i]);
            }
            for (; j < end; j += 2) {
                const int s0 = col[j];
                const u16x8 u0 = *(const u16x8*)(fbp + (size_t)s0 * D);
#pragma unroll
                for (int i = 0; i < 8; ++i) a0[i] += bf2f(u0[i]);
            }

            const float invd = 1.0f / fmaxf((float)(end - beg), 1.0f);
            u16x8 o;
#pragma unroll
            for (int i = 0; i < 8; ++i) {
                float v = (a0[i] + a1[i]) + (a2[i] + a3[i]);
                v += __shfl_xor(v, 32, 64);
                o[i] = f2bf(v * invd);
            }
            if (half == 0)
                *(u16x8*)(&Hs[local][chunk * 8]) = o;
        }
    }
    __syncthreads();

    // ---------------- phase 2: 64x64 MFMA GEMM ----------------
    const int c0 = wid * 64;
    const int nl = lane & 15;
    const int kg = lane >> 4;

    f32x4 acc[4][4];
#pragma unroll
    for (int m = 0; m < 4; ++m)
#pragma unroll
        for (int n = 0; n < 4; ++n) acc[m][n] = (f32x4){0.f, 0.f, 0.f, 0.f};

    size_t aoff[4];
#pragma unroll
    for (int m = 0; m < 4; ++m) {
        int r = row0 + m * 16 + nl;
        if (r > N_NODES - 1) r = N_NODES - 1;
        aoff[m] = (size_t)r * D + kg * 8;
    }

#pragma unroll
    for (int hf = 0; hf < 2; ++hf) {
        const unsigned short* wh = wb + hf * 65536 + (size_t)(c0 + nl) * 256 + kg * 8;
#pragma unroll
        for (int kk = 0; kk < 8; ++kk) {
            const int kb = kk * 32;
            s16x8 afrag[4];
#pragma unroll
            for (int m = 0; m < 4; ++m) {
                if (hf == 0)
                    afrag[m] = *(const s16x8*)(fb + aoff[m] + kb);
                else
                    afrag[m] = *(const s16x8*)(&Hs[m * 16 + nl][kg * 8 + kb]);
            }
            s16x8 bfrag[4];
#pragma unroll
            for (int n = 0; n < 4; ++n)
                bfrag[n] = *(const s16x8*)(wh + n * 4096 + kb);
#pragma unroll
            for (int m = 0; m < 4; ++m)
#pragma unroll
                for (int n = 0; n < 4; ++n)
                    acc[m][n] = __builtin_amdgcn_mfma_f32_16x16x32_bf16(
                        afrag[m], bfrag[n], acc[m][n], 0, 0, 0);
        }
    }

#pragma unroll
    for (int n = 0; n < 4; ++n) {
        const float bias = b_self[c0 + n * 16 + nl];
#pragma unroll
        for (int m = 0; m < 4; ++m) {
            const int rbase = row0 + m * 16 + kg * 4;
#pragma unroll
            for (int r = 0; r < 4; ++r) {
                const int row = rbase + r;
                if (row < N_NODES)
                    outp[(size_t)row * D + c0 + n * 16 + nl] = acc[m][n][r] + bias;
            }
        }
    }
}

// ---------------------------------------------------------------------------
// MID tier: fp32 gather + in-place bf16 GEMM (H fp32 in out)
// ---------------------------------------------------------------------------
__global__ __launch_bounds__(256) void aggregate_f32_kernel(
    const float* __restrict__ feat, const int* __restrict__ row_ptr,
    const int* __restrict__ col, float* __restrict__ outf)
{
    const int node = (blockIdx.x * blockDim.x + threadIdx.x) >> 6;
    const int lane = threadIdx.x & 63;
    if (node >= N_NODES) return;
    const int beg = row_ptr[node], end = row_ptr[node + 1];

    float4 a0 = make_float4(0.f, 0.f, 0.f, 0.f);
    float4 a1 = make_float4(0.f, 0.f, 0.f, 0.f);
    float4 a2 = make_float4(0.f, 0.f, 0.f, 0.f);
    float4 a3 = make_float4(0.f, 0.f, 0.f, 0.f);

#define ACC(acc, s)                                                          \
    do {                                                                     \
        const float4 v = ((const float4*)(feat + (size_t)(s) * D))[lane];    \
        acc.x += v.x; acc.y += v.y; acc.z += v.z; acc.w += v.w;              \
    } while (0)

    int j = beg;
    for (; j + 3 < end; j += 4) {
        const int s0 = col[j], s1 = col[j + 1], s2 = col[j + 2], s3 = col[j + 3];
        ACC(a0, s0); ACC(a1, s1); ACC(a2, s2); ACC(a3, s3);
    }
    for (; j < end; ++j) { const int s0 = col[j]; ACC(a0, s0); }
#undef ACC

    const float invd = 1.0f / fmaxf((float)(end - beg), 1.0f);
    float4 r;
    r.x = ((a0.x + a1.x) + (a2.x + a3.x)) * invd;
    r.y = ((a0.y + a1.y) + (a2.y + a3.y)) * invd;
    r.z = ((a0.z + a1.z) + (a2.z + a3.z)) * invd;
    r.w = ((a0.w + a1.w) + (a2.w + a3.w)) * invd;
    ((float4*)(outf + (size_t)node * D))[lane] = r;
}

__global__ __launch_bounds__(256) void gemm_mfma64_f32h_kernel(
    const float* __restrict__ feat,
    const unsigned short* __restrict__ wb,
    const float* __restrict__ b_self,
    const float* h32,                      // aliases outp (in-place)
    float* outp)
{
    const int lane = threadIdx.x & 63;
    const int wslice = threadIdx.x >> 6;
    const int row0 = blockIdx.x * 64;
    const int c0 = wslice * 64;
    const int nl = lane & 15;
    const int kg = lane >> 4;

    f32x4 acc[4][4];
#pragma unroll
    for (int m = 0; m < 4; ++m)
#pragma unroll
        for (int n = 0; n < 4; ++n) acc[m][n] = (f32x4){0.f, 0.f, 0.f, 0.f};

    size_t aoff[4];
#pragma unroll
    for (int m = 0; m < 4; ++m) {
        int r = row0 + m * 16 + nl;
        if (r > N_NODES - 1) r = N_NODES - 1;
        aoff[m] = (size_t)r * D + kg * 8;
    }

#pragma unroll
    for (int hf = 0; hf < 2; ++hf) {
        const unsigned short* wh = wb + hf * 65536 + (size_t)(c0 + nl) * 256 + kg * 8;
#pragma unroll
        for (int kk = 0; kk < 8; ++kk) {
            const int kb = kk * 32;
            s16x8 afrag[4];
#pragma unroll
            for (int m = 0; m < 4; ++m) {
                const float* ap = hf == 0 ? (const float*)feat : h32;
                const f32x8 av = *(const f32x8*)(ap + aoff[m] + kb);
#pragma unroll
                for (int i = 0; i < 8; ++i) afrag[m][i] = (short)f2bf(av[i]);
            }
            s16x8 bfrag[4];
#pragma unroll
            for (int n = 0; n < 4; ++n)
                bfrag[n] = *(const s16x8*)(wh + n * 4096 + kb);
#pragma unroll
            for (int m = 0; m < 4; ++m)
#pragma unroll
                for (int n = 0; n < 4; ++n)
                    acc[m][n] = __builtin_amdgcn_mfma_f32_16x16x32_bf16(
                        afrag[m], bfrag[n], acc[m][n], 0, 0, 0);
        }
    }

    __syncthreads();   // in-place: reads of out rows done before stores

#pragma unroll
    for (int n = 0; n < 4; ++n) {
        const float bias = b_self[c0 + n * 16 + nl];
#pragma unroll
        for (int m = 0; m < 4; ++m) {
            const int rbase = row0 + m * 16 + kg * 4;
#pragma unroll
            for (int r = 0; r < 4; ++r) {
                const int row = rbase + r;
                if (row < N_NODES)
                    outp[(size_t)row * D + c0 + n * 16 + nl] = acc[m][n][r] + bias;
            }
        }
    }
}

// ---------------------------------------------------------------------------
// Atomic fallback path (tiny ws)
// ---------------------------------------------------------------------------
__global__ __launch_bounds__(256) void scatter_kernel(
    const float* __restrict__ feat, const int* __restrict__ src,
    const int* __restrict__ dst, float* __restrict__ S, float* __restrict__ deg)
{
    const int gtid = blockIdx.x * blockDim.x + threadIdx.x;
    const int wave = gtid >> 6;
    const int lane = gtid & 63;
    const int nwaves = (gridDim.x * blockDim.x) >> 6;
    for (int e = wave; e < N_EDGES; e += nwaves) {
        const int s = src[e];
        const int d = dst[e];
        if (lane == 0) unsafeAtomicAdd(&deg[d], 1.0f);
        const float4 v = ((const float4*)(feat + (size_t)s * D))[lane];
        float* o = S + (size_t)d * D + lane * 4;
        unsafeAtomicAdd(o + 0, v.x);
        unsafeAtomicAdd(o + 1, v.y);
        unsafeAtomicAdd(o + 2, v.z);
        unsafeAtomicAdd(o + 3, v.w);
    }
}

#define BM 64
#define BK 16

__global__ __launch_bounds__(256) void fused_gemm_f32(
    const float* __restrict__ feat, const float* __restrict__ w_neigh,
    const float* __restrict__ w_self, const float* __restrict__ b_self,
    const float* __restrict__ deg, float* out)
{
    __shared__ float At[BK][BM + 4];
    __shared__ float Bt[BK][256];

    const int tid = threadIdx.x;
    const int i0 = blockIdx.x * BM;
    const int trow = tid >> 4;
    const int tcol = tid & 15;
    const int m_load = tid >> 2;
    const int kq = tid & 3;

    const int arow = i0 + m_load;
    const bool arow_ok = arow < N_NODES;
    float invd = 1.0f;
    if (arow_ok) invd = 1.0f / fmaxf(deg[arow], 1.0f);

    float acc[4][16];
#pragma unroll
    for (int r = 0; r < 4; ++r)
#pragma unroll
        for (int c = 0; c < 16; ++c) acc[r][c] = 0.0f;

    for (int kc = 0; kc < (2 * D) / BK; ++kc) {
        const int kb = kc * BK;
        const bool self_part = (kb < D);
        const int kbase = self_part ? kb : (kb - D);

        float4 va = make_float4(0.f, 0.f, 0.f, 0.f);
        if (arow_ok) {
            const float* ap = self_part ? feat : out;
            va = *(const float4*)(ap + (size_t)arow * D + kbase + kq * 4);
            if (!self_part) { va.x *= invd; va.y *= invd; va.z *= invd; va.w *= invd; }
        }
        const float* W = self_part ? w_self : w_neigh;
        const float4* wp = (const float4*)(W + (size_t)tid * D + kbase);
        const float4 w0 = wp[0], w1 = wp[1], w2 = wp[2], w3 = wp[3];

        __syncthreads();
        At[kq * 4 + 0][m_load] = va.x;
        At[kq * 4 + 1][m_load] = va.y;
        At[kq * 4 + 2][m_load] = va.z;
        At[kq * 4 + 3][m_load] = va.w;
        Bt[ 0][tid] = w0.x; Bt[ 1][tid] = w0.y; Bt[ 2][tid] = w0.z; Bt[ 3][tid] = w0.w;
        Bt[ 4][tid] = w1.x; Bt[ 5][tid] = w1.y; Bt[ 6][tid] = w1.z; Bt[ 7][tid] = w1.w;
        Bt[ 8][tid] = w2.x; Bt[ 9][tid] = w2.y; Bt[10][tid] = w2.z; Bt[11][tid] = w2.w;
        Bt[12][tid] = w3.x; Bt[13][tid] = w3.y; Bt[14][tid] = w3.z; Bt[15][tid] = w3.w;
        __syncthreads();

#pragma unroll
        for (int k = 0; k < BK; ++k) {
            const float4 a = *(const float4*)&At[k][trow * 4];
            float4 b[4];
#pragma unroll
            for (int g = 0; g < 4; ++g)
                b[g] = *(const float4*)&Bt[k][g * 64 + tcol * 4];
            const float av[4] = {a.x, a.y, a.z, a.w};
#pragma unroll
            for (int r = 0; r < 4; ++r)
#pragma unroll
                for (int g = 0; g < 4; ++g) {
                    acc[r][g * 4 + 0] = fmaf(av[r], b[g].x, acc[r][g * 4 + 0]);
                    acc[r][g * 4 + 1] = fmaf(av[r], b[g].y, acc[r][g * 4 + 1]);
                    acc[r][g * 4 + 2] = fmaf(av[r], b[g].z, acc[r][g * 4 + 2]);
                    acc[r][g * 4 + 3] = fmaf(av[r], b[g].w, acc[r][g * 4 + 3]);
                }
        }
    }

    float4 bias[4];
#pragma unroll
    for (int g = 0; g < 4; ++g)
        bias[g] = *(const float4*)&b_self[g * 64 + tcol * 4];

#pragma unroll
    for (int r = 0; r < 4; ++r) {
        const int row = i0 + trow * 4 + r;
        if (row < N_NODES) {
            float* op = out + (size_t)row * D;
#pragma unroll
            for (int g = 0; g < 4; ++g) {
                float4 v;
                v.x = acc[r][g * 4 + 0] + bias[g].x;
                v.y = acc[r][g * 4 + 1] + bias[g].y;
                v.z = acc[r][g * 4 + 2] + bias[g].z;
                v.w = acc[r][g * 4 + 3] + bias[g].w;
                *(float4*)(op + g * 64 + tcol * 4) = v;
            }
        }
    }
}

// ---------------------------------------------------------------------------
extern "C" void kernel_launch(void* const* d_in, const int* in_sizes, int n_in,
                              void* d_out, int out_size, void* d_ws, size_t ws_size,
                              hipStream_t stream) {
    const float* feat    = (const float*)d_in[0];
    const int*   src     = (const int*)d_in[1];
    const int*   dst     = (const int*)d_in[2];
    const float* w_neigh = (const float*)d_in[3];
    const float* w_self  = (const float*)d_in[4];
    const float* b_self  = (const float*)d_in[5];
    float* out = (float*)d_out;

    const int eblocks = (N_EDGES + 255) / 256;
    const int ablocks = (N_NODES * 64 + 255) / 256;        // 1 wave/node
    const int gblocks = (N_NODES + 63) / 64;               // 64 rows/block

    if (ws_size >= NEED_MID) {
        int* wsI     = (int*)d_ws;
        int* counts  = wsI + WS_COUNTS;
        int* row_ptr = wsI + WS_ROWPTR;
        int* col     = wsI + WS_COL;
        int* part    = wsI + WS_PART;
        unsigned short* wb = (unsigned short*)((char*)d_ws + WB_BYTE);
        unsigned short* fb = (unsigned short*)((char*)d_ws + FB_BYTE);

        hipMemsetAsync(counts, 0, N_NODES * sizeof(int), stream);
        hist_kernel<<<eblocks, 256, 0, stream>>>(dst, counts);
        scan_block_kernel<<<SCAN_NB, 1024, 0, stream>>>(counts, row_ptr, part);
        scan_partials_kernel<<<1, 128, 0, stream>>>(part);
        scan_add_kernel<<<SCAN_NB, 1024, 0, stream>>>(part, row_ptr);
        hipMemsetAsync(counts, 0, N_NODES * sizeof(int), stream);
        fill_kernel<<<eblocks, 256, 0, stream>>>(src, dst, row_ptr, counts, col);

        if (ws_size >= NEED_FULL) {
            cvt_kernel<<<FBLOCKS + 128, 256, 0, stream>>>(feat, w_self, w_neigh, fb, wb);
            fused_agg_gemm_kernel<<<gblocks, 256, 0, stream>>>(
                fb, wb, b_self, row_ptr, col, out);
        } else {
            wcvt_kernel<<<128, 256, 0, stream>>>(w_self, w_neigh, wb);
            aggregate_f32_kernel<<<ablocks, 256, 0, stream>>>(
                feat, row_ptr, col, out);
            gemm_mfma64_f32h_kernel<<<gblocks, 256, 0, stream>>>(
                feat, wb, b_self, out, out);
        }
    } else {
        float* deg = (float*)d_ws;
        hipMemsetAsync(out, 0, (size_t)N_NODES * D * sizeof(float), stream);
        hipMemsetAsync(deg, 0, (size_t)N_NODES * sizeof(float), stream);
        scatter_kernel<<<4096, 256, 0, stream>>>(feat, src, dst, out, deg);
        fused_gemm_f32<<<(N_NODES + BM - 1) / BM, 256, 0, stream>>>(
            feat, w_neigh, w_self, b_self, deg, out);
    }
}